// Round 4
// baseline (24344.609 us; speedup 1.0000x reference)
//
#include <hip/hip_runtime.h>
#include <math.h>

#define NV 500
#define NB 32
#define NT 24
#define NH 64

typedef _Float16 f16;
typedef _Float16 f16x8 __attribute__((ext_vector_type(8)));
typedef _Float16 f16x4 __attribute__((ext_vector_type(4)));
typedef float    f32x4 __attribute__((ext_vector_type(4)));

__device__ __forceinline__ float sigm(float x){ return 1.f/(1.f+expf(-x)); }

// ======================= grid barrier (persistent kernels) =======================
// Monotonic-generation barrier. Writers: __threadfence (device) before arrival;
// last arriver release-stores the generation; waiters acquire-load it.
__device__ __forceinline__ void gbar(int* cnt, int* gen, int g, int nblk)
{
    __syncthreads();
    if (threadIdx.x == 0) {
        __threadfence();
        int old = __hip_atomic_fetch_add(cnt, 1, __ATOMIC_ACQ_REL, __HIP_MEMORY_SCOPE_AGENT);
        if (old == g*nblk - 1) {
            __hip_atomic_store(gen, g, __ATOMIC_RELEASE, __HIP_MEMORY_SCOPE_AGENT);
        } else {
            while (__hip_atomic_load(gen, __ATOMIC_ACQUIRE, __HIP_MEMORY_SCOPE_AGENT) < g)
                __builtin_amdgcn_s_sleep(4);
        }
    }
    __syncthreads();
}

__global__ void k_zero(int* p){ p[threadIdx.x] = 0; }

// ======================= prep kernels =======================
// tiled f32 GEMM: A2[s] = A[s] @ A[s]; grid (8,8,3), 64x64 tile
__global__ __launch_bounds__(256)
void k_a2(const float* __restrict__ A, float* __restrict__ A2)
{
    __shared__ float tA[64][33];
    __shared__ float tB[32][65];
    const int s = blockIdx.z;
    const int r0 = blockIdx.y*64, w0 = blockIdx.x*64;
    const float* As = A + (size_t)s*500*500;
    const int tid = threadIdx.x;
    const int ty = tid>>4, tx = tid&15;
    float acc[4][4] = {};
    for (int k0 = 0; k0 < 500; k0 += 32) {
        __syncthreads();
        for (int e = tid; e < 64*32; e += 256) {
            int r = e>>5, kk = e&31;
            float v = 0.f;
            if (r0+r < 500 && k0+kk < 500) v = As[(size_t)(r0+r)*500 + k0+kk];
            tA[r][kk] = v;
        }
        for (int e = tid; e < 32*64; e += 256) {
            int kk = e>>6, ww = e&63;
            float v = 0.f;
            if (k0+kk < 500 && w0+ww < 500) v = As[(size_t)(k0+kk)*500 + w0+ww];
            tB[kk][ww] = v;
        }
        __syncthreads();
        #pragma unroll 8
        for (int kk = 0; kk < 32; kk++) {
            float a0=tA[ty][kk], a1=tA[ty+16][kk], a2=tA[ty+32][kk], a3=tA[ty+48][kk];
            float b0=tB[kk][tx], b1=tB[kk][tx+16], b2=tB[kk][tx+32], b3=tB[kk][tx+48];
            acc[0][0]+=a0*b0; acc[0][1]+=a0*b1; acc[0][2]+=a0*b2; acc[0][3]+=a0*b3;
            acc[1][0]+=a1*b0; acc[1][1]+=a1*b1; acc[1][2]+=a1*b2; acc[1][3]+=a1*b3;
            acc[2][0]+=a2*b0; acc[2][1]+=a2*b1; acc[2][2]+=a2*b2; acc[2][3]+=a2*b3;
            acc[3][0]+=a3*b0; acc[3][1]+=a3*b1; acc[3][2]+=a3*b2; acc[3][3]+=a3*b3;
        }
    }
    #pragma unroll
    for (int i=0;i<4;i++) {
        int r = r0 + ty + 16*i;
        if (r >= 500) continue;
        #pragma unroll
        for (int j=0;j<4;j++) {
            int ww = w0 + tx + 16*j;
            if (ww < 500) A2[((size_t)s*500 + r)*500 + ww] = acc[i][j];
        }
    }
}

__global__ void k_acat(const float* __restrict__ A, const float* __restrict__ A2,
                       f16* __restrict__ AcatT)
{
    int idx = blockIdx.x*256 + threadIdx.x;
    if (idx >= 3072*512) return;
    int k = idx & 511;     // v
    int n = idx >> 9;      // j*512 + w
    int j = n >> 9, wv = n & 511;
    float val = 0.f;
    if (k < 500 && wv < 500) {
        int s = j >> 1;
        const float* M = (j & 1) ? A2 : A;
        val = M[((size_t)s*500 + k)*500 + wv];
    }
    AcatT[idx] = (f16)val;
}

__global__ void k_f2h(const float* __restrict__ src, f16* __restrict__ dst, int n)
{
    int idx = blockIdx.x*256 + threadIdx.x;
    if (idx < n) dst[idx] = (f16)src[idx];
}

// ======================= diffusion GEMM tile (device fn, proven structure) =======================
__device__ __forceinline__ void diff_tile(int n0, int m0,
    const f16* __restrict__ Acv, const f16* __restrict__ Bt, f16* __restrict__ fout,
    int Mtot, int C, int G, f16* lA, f16* lB)
{
    const int tid = threadIdx.x;
    const int r0 = tid>>2, c0 = tid&3;
    const int swz0 = r0*32 + ((c0 ^ ((r0>>1)&3))<<3);
    const int swz1 = swz0 + 64*32;
    int mA0 = m0 + r0;      if (mA0 > Mtot-1) mA0 = Mtot-1;
    int mA1 = m0 + r0 + 64; if (mA1 > Mtot-1) mA1 = Mtot-1;
    const f16* gA0 = Acv + (size_t)mA0*512 + c0*8;
    const f16* gA1 = Acv + (size_t)mA1*512 + c0*8;
    const f16* gB0 = Bt + (size_t)(n0+r0)*512 + c0*8;
    const f16* gB1 = Bt + (size_t)(n0+r0+64)*512 + c0*8;

    const int w = tid>>6, lane = tid&63;
    const int wr = (w>>1)<<6, wc = (w&1)<<6;
    const int fm = lane&15, fk = lane>>4;
    const int fch = (fk ^ ((fm>>1)&3))<<3;

    f32x4 acc[4][4];
    #pragma unroll
    for (int i=0;i<4;i++)
        #pragma unroll
        for (int j=0;j<4;j++) acc[i][j] = (f32x4){0.f,0.f,0.f,0.f};

    f32x4 ra0 = *(const f32x4*)gA0, ra1 = *(const f32x4*)gA1;
    f32x4 rb0 = *(const f32x4*)gB0, rb1 = *(const f32x4*)gB1;

    for (int ks = 0; ks < 16; ks++) {
        __syncthreads();
        *(f32x4*)(lA + swz0) = ra0;  *(f32x4*)(lA + swz1) = ra1;
        *(f32x4*)(lB + swz0) = rb0;  *(f32x4*)(lB + swz1) = rb1;
        if (ks < 15) {
            int o = (ks+1)*32;
            ra0 = *(const f32x4*)(gA0 + o); ra1 = *(const f32x4*)(gA1 + o);
            rb0 = *(const f32x4*)(gB0 + o); rb1 = *(const f32x4*)(gB1 + o);
        }
        __syncthreads();
        f16x8 af[4], bf[4];
        #pragma unroll
        for (int i=0;i<4;i++) af[i] = *(const f16x8*)(lA + (wr + i*16 + fm)*32 + fch);
        #pragma unroll
        for (int j=0;j<4;j++) bf[j] = *(const f16x8*)(lB + (wc + j*16 + fm)*32 + fch);
        #pragma unroll
        for (int i=0;i<4;i++)
            #pragma unroll
            for (int j=0;j<4;j++)
                acc[i][j] = __builtin_amdgcn_mfma_f32_16x16x32_f16(af[i], bf[j], acc[i][j], 0, 0, 0);
    }

    #pragma unroll
    for (int j=0;j<4;j++) {
        int col = n0 + wc + j*16 + fm;
        int jb = col >> 9, wv = col & 511;
        if (wv >= 500) continue;
        #pragma unroll
        for (int i=0;i<4;i++) {
            int mb = m0 + wr + i*16 + fk*4;
            if (C == 64) {
                if (mb >= Mtot) continue;
                int b = mb >> 6, c = mb & 63;
                f16x4 h4;
                h4[0]=(f16)acc[i][j][0]; h4[1]=(f16)acc[i][j][1];
                h4[2]=(f16)acc[i][j][2]; h4[3]=(f16)acc[i][j][3];
                *(f16x4*)(fout + ((size_t)b*512 + wv)*G + C + jb*C + c) = h4;
            } else {
                #pragma unroll
                for (int r=0;r<4;r++) {
                    int m = mb + r;
                    if (m < Mtot) {
                        int b = m / C, c = m - b*C;
                        fout[((size_t)b*512 + wv)*G + C + jb*C + c] = (f16)acc[i][j][r];
                    }
                }
            }
        }
    }
}

// ======================= persistent big layer (layers 1-3) =======================
// 256 blocks. Per t: phase1 = diffusion (384 tiles; block does bid and bid+256 if bid<128),
// barrier, phase2 = gates GEMM + LSTM + next comb (tile = bid: vtile=bid&7, b=bid>>3), barrier.
__global__ __launch_bounds__(256, 2)
void k_big(const f16* __restrict__ AcatT, const f16* __restrict__ Wg,
           const float* __restrict__ bg, float* __restrict__ cst,
           const f16* __restrict__ Xbuf, long xstride,
           f16* __restrict__ hsave, long hstride, int hlastonly,
           const float* __restrict__ Wo3, const float* __restrict__ bo3,
           float* __restrict__ out,
           f16* __restrict__ featsT, f16* __restrict__ ccv,
           int* __restrict__ bcnt, int* __restrict__ bgen)
{
    __shared__ union {
        struct { f16 lA[128*32]; f16 lB[128*32]; } d;                    // 16 KB
        struct { f16 lA[64*32]; f16 lB[256*32]; f16 ExF[4*64*68];
                 float bgS[256]; f16 combS[64*68]; } g;                  // 63.5 KB
    } S;
    const int tid = threadIdx.x;
    const int w = tid>>6, lane = tid&63;
    const int fm = lane&15, fk = lane>>4;
    const int fch = (fk ^ ((fm>>1)&3))<<3;
    int gc = 0;

    for (int t = 0; t < NT; t++) {
        // ---------- phase 1: diffusion ----------
        diff_tile((blockIdx.x%24)*128, (blockIdx.x/24)*128, ccv, AcatT, featsT,
                  2048, 64, 448, S.d.lA, S.d.lB);
        if (blockIdx.x < 128) {
            int tl = blockIdx.x + 256;
            diff_tile((tl%24)*128, (tl/24)*128, ccv, AcatT, featsT,
                      2048, 64, 448, S.d.lA, S.d.lB);
        }
        gbar(bcnt, bgen, ++gc, 256);

        // ---------- phase 2: gates + LSTM + comb ----------
        {
            const int m0 = (blockIdx.x & 7)<<6;
            const int b  = blockIdx.x >> 3;
            const f16* Ab = featsT + (size_t)b*512*448;
            S.g.bgS[tid] = bg[tid];
            const int r0 = tid>>2, c0 = tid&3;
            const int swz = r0*32 + ((c0 ^ ((r0>>1)&3))<<3);
            const f16* gA = Ab + (size_t)(m0+r0)*448 + c0*8;
            const f16* gB = Wg + (size_t)r0*448 + c0*8;
            const int wc = w<<6;

            f32x4 acc[4][4];
            #pragma unroll
            for (int i=0;i<4;i++)
                #pragma unroll
                for (int j=0;j<4;j++) acc[i][j] = (f32x4){0.f,0.f,0.f,0.f};

            f32x4 ra  = *(const f32x4*)gA;
            f32x4 rb0 = *(const f32x4*)gB;
            f32x4 rb1 = *(const f32x4*)(gB + (size_t)64*448);
            f32x4 rb2 = *(const f32x4*)(gB + (size_t)128*448);
            f32x4 rb3 = *(const f32x4*)(gB + (size_t)192*448);

            for (int ks = 0; ks < 14; ks++) {
                __syncthreads();
                *(f32x4*)(S.g.lA + swz) = ra;
                *(f32x4*)(S.g.lB + swz)          = rb0;
                *(f32x4*)(S.g.lB + 64*32 + swz)  = rb1;
                *(f32x4*)(S.g.lB + 128*32 + swz) = rb2;
                *(f32x4*)(S.g.lB + 192*32 + swz) = rb3;
                if (ks < 13) {
                    int o = (ks+1)*32;
                    ra  = *(const f32x4*)(gA + o);
                    rb0 = *(const f32x4*)(gB + o);
                    rb1 = *(const f32x4*)(gB + (size_t)64*448 + o);
                    rb2 = *(const f32x4*)(gB + (size_t)128*448 + o);
                    rb3 = *(const f32x4*)(gB + (size_t)192*448 + o);
                }
                __syncthreads();
                f16x8 af[4], bf[4];
                #pragma unroll
                for (int i=0;i<4;i++) af[i] = *(const f16x8*)(S.g.lA + (i*16 + fm)*32 + fch);
                #pragma unroll
                for (int j=0;j<4;j++) bf[j] = *(const f16x8*)(S.g.lB + (wc + j*16 + fm)*32 + fch);
                #pragma unroll
                for (int i=0;i<4;i++)
                    #pragma unroll
                    for (int j=0;j<4;j++)
                        acc[i][j] = __builtin_amdgcn_mfma_f32_16x16x32_f16(af[i], bf[j], acc[i][j], 0, 0, 0);
            }

            // exchange accumulators (f16): ExF[quad w][vertex][chan]
            __syncthreads();
            #pragma unroll
            for (int i=0;i<4;i++)
                #pragma unroll
                for (int j=0;j<4;j++)
                    #pragma unroll
                    for (int r=0;r<4;r++)
                        S.g.ExF[((w<<6) + i*16 + (fk<<2) + r)*68 + (j<<4) + fm] = (f16)acc[i][j][r];
            __syncthreads();

            const int vl = tid>>2, p = tid&3;
            const int v = m0 + vl;
            const size_t row = (size_t)b*512 + v;
            alignas(16) f16 gq[4][16];
            #pragma unroll
            for (int q=0;q<4;q++) {
                *(f32x4*)&gq[q][0] = *(const f32x4*)(S.g.ExF + (q*64+vl)*68 + (p<<4));
                *(f32x4*)&gq[q][8] = *(const f32x4*)(S.g.ExF + (q*64+vl)*68 + (p<<4) + 8);
            }

            float hy[16];
            float* cp = cst + row*64 + (p<<4);
            const int first = (t == 0);
            #pragma unroll
            for (int k4=0;k4<4;k4++) {
                f32x4 cx4 = first ? (f32x4){0.f,0.f,0.f,0.f} : *(const f32x4*)(cp + k4*4);
                f32x4 cy4;
                #pragma unroll
                for (int e=0;e<4;e++) {
                    int kk = k4*4+e, c = (p<<4) + kk;
                    float gi = (float)gq[0][kk] + S.g.bgS[c];
                    float gf = (float)gq[1][kk] + S.g.bgS[64+c];
                    float gcv= (float)gq[2][kk] + S.g.bgS[128+c];
                    float go = (float)gq[3][kk] + S.g.bgS[192+c];
                    float cy = sigm(gf)*cx4[e] + sigm(gi)*gcv;
                    cy4[e] = cy;
                    hy[kk] = sigm(go)*tanhf(cy);
                }
                *(f32x4*)(cp + k4*4) = cy4;
            }

            if (hsave && (!hlastonly || t == 23)) {
                alignas(16) f16 tmp[16];
                #pragma unroll
                for (int k=0;k<16;k++) tmp[k] = (f16)hy[k];
                f16* hp = hsave + (hlastonly ? 0 : (size_t)t*hstride) + row*64 + (p<<4);
                *(f32x4*)hp = *(f32x4*)tmp;
                *(f32x4*)(hp+8) = *(f32x4*)(tmp+8);
            }

            if (out) {
                float r0s = 0.f, r1s = 0.f;
                #pragma unroll
                for (int k=0;k<16;k++){ r0s += Wo3[(p<<4)+k]*hy[k]; r1s += Wo3[64+(p<<4)+k]*hy[k]; }
                r0s += __shfl_xor(r0s, 1, 64); r0s += __shfl_xor(r0s, 2, 64);
                r1s += __shfl_xor(r1s, 1, 64); r1s += __shfl_xor(r1s, 2, 64);
                if (p == 0 && v < 500) {
                    out[((size_t)(b*2+0)*500 + v)*24 + t] = r0s + bo3[0];
                    out[((size_t)(b*2+1)*500 + v)*24 + t] = r1s + bo3[1];
                }
            }

            if (t < 23) {
                const f16* Xn = Xbuf + (xstride ? (size_t)(t+1)*xstride : 0);
                alignas(16) f16 c16[16];
                if (v < 500) {
                    const f16* xp = Xn + row*64 + (p<<4);
                    alignas(16) f16 xv[16];
                    *(f32x4*)xv = *(const f32x4*)xp;
                    *(f32x4*)(xv+8) = *(const f32x4*)(xp+8);
                    #pragma unroll
                    for (int k=0;k<16;k++) c16[k] = (f16)((float)xv[k] + hy[k]);
                } else {
                    #pragma unroll
                    for (int k=0;k<16;k++) c16[k] = (f16)0.f;
                }
                f16* fp = featsT + row*448 + (p<<4);
                *(f32x4*)fp = *(f32x4*)c16;
                *(f32x4*)(fp+8) = *(f32x4*)(c16+8);
                #pragma unroll
                for (int k=0;k<16;k++) S.g.combS[vl*68 + (p<<4) + k] = c16[k];
                __syncthreads();
                const int c = tid>>2, jj = tid&3;
                alignas(16) f16 tmp[16];
                #pragma unroll
                for (int k=0;k<16;k++) tmp[k] = S.g.combS[(jj*16+k)*68 + c];
                f16* dst = ccv + ((size_t)b*64 + c)*512 + m0 + jj*16;
                *(f32x4*)dst = *(f32x4*)tmp;
                *(f32x4*)(dst+8) = *(f32x4*)(tmp+8);
            }
        }
        gbar(bcnt, bgen, ++gc, 256);
    }
}

// ======================= persistent layer 0 =======================
__global__ __launch_bounds__(256, 2)
void k_l0(const f16* __restrict__ AcatT, f16* __restrict__ ccv0, f16* __restrict__ f0T,
          const float* __restrict__ Wg0, const float* __restrict__ bg0,
          float* __restrict__ cst0, float* __restrict__ hs0T,
          const float* __restrict__ XE, int* __restrict__ bcnt, int* __restrict__ bgen)
{
    __shared__ union {
        struct { f16 lA[128*32]; f16 lB[128*32]; } d;
        struct { float WgS[24*42]; float bgS[24]; } g;
    } S;
    const int tid = threadIdx.x;
    int gc = 0;
    for (int t = 0; t < NT; t++) {
        if (blockIdx.x < 48)
            diff_tile((blockIdx.x%24)*128, (blockIdx.x/24)*128, ccv0, AcatT, f0T,
                      192, 6, 42, S.d.lA, S.d.lB);
        gbar(bcnt, bgen, ++gc, 256);
        {
            for (int i = tid; i < 24*42; i += 256) S.g.WgS[i] = Wg0[i];
            if (tid < 24) S.g.bgS[tid] = bg0[tid];
            __syncthreads();
            int id = blockIdx.x*256 + tid;
            if (id < NB*500) {
                int b = id / 500, v = id - b*500;
                const f16* fp = f0T + ((size_t)b*512 + v)*42;
                float fv[42];
                #pragma unroll
                for (int g = 0; g < 42; g++) fv[g] = (float)fp[g];
                float gates[24];
                #pragma unroll
                for (int o = 0; o < 24; o++) {
                    float a = S.g.bgS[o];
                    #pragma unroll
                    for (int g = 0; g < 42; g++) a += S.g.WgS[o*42+g]*fv[g];
                    gates[o] = a;
                }
                size_t hrow = (((size_t)t*NB + b)*512 + v)*6;
                const float* xe = XE + (((size_t)(t+1)*NB + b)*512 + v)*6;
                #pragma unroll
                for (int c = 0; c < 6; c++) {
                    size_t ci = ((size_t)b*500 + v)*6 + c;
                    float cx = t ? cst0[ci] : 0.f;
                    float cy = sigm(gates[6+c])*cx + sigm(gates[c])*gates[12+c];
                    cst0[ci] = cy;
                    float h = sigm(gates[18+c])*tanhf(cy);
                    hs0T[hrow + c] = h;
                    if (t < 23) {
                        float cmb = xe[c] + h;
                        f0T[((size_t)b*512 + v)*42 + c] = (f16)cmb;
                        ccv0[((size_t)b*6 + c)*512 + v] = (f16)cmb;
                    }
                }
            }
        }
        gbar(bcnt, bgen, ++gc, 256);
    }
}

// ======================= seed comb for t=0 (big layers) =======================
__global__ __launch_bounds__(256)
void k_seed(const f16* __restrict__ X0, f16* __restrict__ fT, f16* __restrict__ ccv)
{
    __shared__ f16 combS[64*68];
    const int b = blockIdx.y, v0 = blockIdx.x*64;
    const int tid = threadIdx.x, vl = tid>>2, p = tid&3;
    const int v = v0 + vl;
    const size_t row = (size_t)b*512 + v;
    alignas(16) f16 c16[16];
    if (v < 500) {
        const f16* xp = X0 + row*64 + p*16;
        *(f32x4*)c16 = *(const f32x4*)xp;
        *(f32x4*)(c16+8) = *(const f32x4*)(xp+8);
    } else {
        #pragma unroll
        for (int k=0;k<16;k++) c16[k] = (f16)0.f;
    }
    f16* fp = fT + row*448 + p*16;
    *(f32x4*)fp = *(f32x4*)c16;
    *(f32x4*)(fp+8) = *(f32x4*)(c16+8);
    #pragma unroll
    for (int k=0;k<16;k++) combS[vl*68 + p*16 + k] = c16[k];
    __syncthreads();
    const int c = tid>>2, j = tid&3;
    alignas(16) f16 tmp[16];
    #pragma unroll
    for (int k=0;k<16;k++) tmp[k] = combS[(j*16+k)*68 + c];
    f16* dst = ccv + ((size_t)b*64 + c)*512 + v0 + j*16;
    *(f32x4*)dst = *(f32x4*)tmp;
    *(f32x4*)(dst+8) = *(f32x4*)(tmp+8);
}

// ======================= MFMA input projection (Cin=64, f16 src) =======================
__global__ __launch_bounds__(256)
void k_xprojm(const f16* __restrict__ src, const f16* __restrict__ WoF,
              const float* __restrict__ bo, const float* __restrict__ se,
              f16* __restrict__ X)
{
    __shared__ f16 lA[128*64];
    __shared__ f16 lB[64*64];
    const int tid = threadIdx.x;
    const size_t m0 = (size_t)blockIdx.x*128;
    const int r0 = tid>>2, c0 = tid&3;
    const int swz = r0*32 + ((c0 ^ ((r0>>1)&3))<<3);
    const f16* gA0 = src + (m0 + r0)*64 + c0*8;
    const f16* gA1 = gA0 + 64*64;
    const f16* gB  = WoF + r0*64 + c0*8;

    *(f32x4*)(lA + swz)               = *(const f32x4*)gA0;
    *(f32x4*)(lA + 2048 + swz)        = *(const f32x4*)gA1;
    *(f32x4*)(lA + 4096 + swz)        = *(const f32x4*)(gA0 + 32);
    *(f32x4*)(lA + 6144 + swz)        = *(const f32x4*)(gA1 + 32);
    *(f32x4*)(lB + swz)               = *(const f32x4*)gB;
    *(f32x4*)(lB + 2048 + swz)        = *(const f32x4*)(gB + 32);
    __syncthreads();

    const int w = tid>>6, lane = tid&63;
    const int wr = w<<5;
    const int fm = lane&15, fk = lane>>4;
    const int fch = (fk ^ ((fm>>1)&3))<<3;

    f32x4 acc[2][4];
    #pragma unroll
    for (int i=0;i<2;i++)
        #pragma unroll
        for (int j=0;j<4;j++) acc[i][j] = (f32x4){0.f,0.f,0.f,0.f};

    #pragma unroll
    for (int ks=0; ks<2; ks++) {
        f16x8 af[2], bf[4];
        #pragma unroll
        for (int i=0;i<2;i++) af[i] = *(const f16x8*)(lA + ks*4096 + (wr + i*16 + fm)*32 + fch);
        #pragma unroll
        for (int j=0;j<4;j++) bf[j] = *(const f16x8*)(lB + ks*2048 + (j*16 + fm)*32 + fch);
        #pragma unroll
        for (int i=0;i<2;i++)
            #pragma unroll
            for (int j=0;j<4;j++)
                acc[i][j] = __builtin_amdgcn_mfma_f32_16x16x32_f16(af[i], bf[j], acc[i][j], 0, 0, 0);
    }
    __syncthreads();

    const int bb = (int)((m0 >> 9) & 31);
    #pragma unroll
    for (int j=0;j<4;j++) {
        const int c = (j<<4) + fm;
        const float bias = bo[c];
        const float sf = se ? se[bb*64 + c] : 1.f;
        #pragma unroll
        for (int i=0;i<2;i++) {
            const int rbase = wr + i*16 + (fk<<2);
            #pragma unroll
            for (int r=0;r<4;r++)
                lA[(rbase + r)*64 + c] = (f16)(sf*(acc[i][j][r] + bias));
        }
    }
    __syncthreads();
    #pragma unroll
    for (int pass=0; pass<4; pass++) {
        int chunk = pass*256 + tid;
        int row = chunk>>3, off = (chunk&7)<<3;
        *(f32x4*)(X + (m0 + row)*64 + off) = *(const f32x4*)(lA + row*64 + off);
    }
}

// ======================= scalar input projection (Cin=6, f32 src, layer 1) =======================
__global__ void k_xproj1(const float* __restrict__ src, const float* __restrict__ Wo,
                         const float* __restrict__ bo, const float* __restrict__ se,
                         f16* __restrict__ X, int total)
{
    int id = blockIdx.x*256 + threadIdx.x;
    if (id >= total) return;
    int c = id & 63;
    size_t row = (size_t)(id >> 6);
    int b = (int)((row >> 9) & 31);
    const float* sp = src + row*6;
    float a = bo[c];
    #pragma unroll
    for (int j=0;j<6;j++) a += Wo[c*6+j]*sp[j];
    X[id] = (f16)(se[b*64+c]*a);
}

// ======================= layer 0 prep =======================
__global__ void k_xe(const float* __restrict__ x, const int* __restrict__ wt,
                     const float* __restrict__ Wemb, float* __restrict__ XE)
{
    int id = blockIdx.x*256 + threadIdx.x;
    if (id >= NT*NB*512) return;
    int v = id & 511; int r = id >> 9; int b = r & 31; int t = r >> 5;
    float vals[6] = {0.f,0.f,0.f,0.f,0.f,0.f};
    if (v < 500) {
        vals[0] = x[((size_t)(b*2+0)*500 + v)*24 + t];
        vals[1] = x[((size_t)(b*2+1)*500 + v)*24 + t];
        int wty = wt[((size_t)b*500 + v)*24 + t];
        vals[2] = Wemb[wty*4+0]; vals[3] = Wemb[wty*4+1];
        vals[4] = Wemb[wty*4+2]; vals[5] = Wemb[wty*4+3];
    }
    float* xe = XE + (size_t)id*6;
    #pragma unroll
    for (int c = 0; c < 6; c++) xe[c] = vals[c];
}

__global__ void k_seed0(const float* __restrict__ XE, f16* __restrict__ f0T,
                        f16* __restrict__ ccv0)
{
    int id = blockIdx.x*256 + threadIdx.x;
    if (id >= NB*512) return;
    int v = id & 511, b = id >> 9;
    const float* xe = XE + (size_t)id*6;
    #pragma unroll
    for (int c = 0; c < 6; c++) {
        f16 h = (v < 500) ? (f16)xe[c] : (f16)0.f;
        f0T[(size_t)id*42 + c] = h;
        ccv0[((size_t)b*6 + c)*512 + v] = h;
    }
}

// ======================= SE path =======================
__global__ void k_mean0(const float* __restrict__ hs0T, float* __restrict__ mean0)
{
    int b = blockIdx.x;
    float acc[6] = {0,0,0,0,0,0};
    for (int i = threadIdx.x; i < 24*500; i += 256) {
        int tt = i/500, v = i - tt*500;
        const float* p = hs0T + (((size_t)tt*NB + b)*512 + v)*6;
        #pragma unroll
        for (int c=0;c<6;c++) acc[c] += p[c];
    }
    __shared__ float red[256];
    for (int c=0;c<6;c++) {
        red[threadIdx.x] = acc[c]; __syncthreads();
        for (int s=128;s>0;s>>=1) { if (threadIdx.x<s) red[threadIdx.x]+=red[threadIdx.x+s]; __syncthreads(); }
        if (threadIdx.x==0) mean0[b*6+c] = red[0]/12000.f;
        __syncthreads();
    }
}

__global__ void k_mean1(const f16* __restrict__ hs1T, float* __restrict__ mean1)
{
    int cg = blockIdx.x, b = blockIdx.y;
    float acc[8] = {0,0,0,0,0,0,0,0};
    for (int i = threadIdx.x; i < 24*500; i += 256) {
        int tt = i/500, v = i - tt*500;
        const f16* p = hs1T + (((size_t)tt*NB + b)*512 + v)*64 + cg*8;
        #pragma unroll
        for (int c=0;c<8;c++) acc[c] += (float)p[c];
    }
    __shared__ float red[256];
    for (int c=0;c<8;c++) {
        red[threadIdx.x] = acc[c]; __syncthreads();
        for (int s=128;s>0;s>>=1) { if (threadIdx.x<s) red[threadIdx.x]+=red[threadIdx.x+s]; __syncthreads(); }
        if (threadIdx.x==0) mean1[b*64 + cg*8 + c] = red[0]/12000.f;
        __syncthreads();
    }
}

__global__ void k_se(const float* __restrict__ meanhs, const float* __restrict__ Wo,
                     const float* __restrict__ bo, int Cin,
                     const float* __restrict__ Wa, const float* __restrict__ Wb,
                     float* __restrict__ se)
{
    int b = blockIdx.x; int c = threadIdx.x;
    __shared__ float y[64]; __shared__ float a[4];
    float acc = bo[c];
    for (int j = 0; j < Cin; j++) acc += Wo[(size_t)c*Cin + j] * meanhs[b*Cin + j];
    y[c] = acc;
    __syncthreads();
    if (c < 4) {
        float s = 0.f;
        for (int j = 0; j < 64; j++) s += Wa[c*64 + j] * y[j];
        a[c] = fmaxf(s, 0.f);
    }
    __syncthreads();
    float s = 0.f;
    #pragma unroll
    for (int j = 0; j < 4; j++) s += Wb[c*4 + j] * a[j];
    se[b*64 + c] = 1.f/(1.f + expf(-s));
}

// ======================= host launch =======================
extern "C" void kernel_launch(void* const* d_in, const int* in_sizes, int n_in,
                              void* d_out, int out_size, void* d_ws, size_t ws_size,
                              hipStream_t stream)
{
    const float* x    = (const float*)d_in[0];
    const float* sup  = (const float*)d_in[1];
    const int*   wt   = (const int*)  d_in[2];
    const float* Wemb = (const float*)d_in[3];
    const float* Wg0  = (const float*)d_in[4];
    const float* bg0  = (const float*)d_in[5];
    const float* Wo0  = (const float*)d_in[6];
    const float* bo0  = (const float*)d_in[7];
    const float* Wa0  = (const float*)d_in[8];
    const float* Wb0  = (const float*)d_in[9];
    const float* Wg1  = (const float*)d_in[10];
    const float* bg1  = (const float*)d_in[11];
    const float* Wo1  = (const float*)d_in[12];
    const float* bo1  = (const float*)d_in[13];
    const float* Wa1  = (const float*)d_in[14];
    const float* Wb1  = (const float*)d_in[15];
    const float* Wg2  = (const float*)d_in[16];
    const float* bg2  = (const float*)d_in[17];
    const float* Wo2  = (const float*)d_in[18];
    const float* bo2  = (const float*)d_in[19];
    const float* Wg3  = (const float*)d_in[20];
    const float* bg3  = (const float*)d_in[21];
    const float* Wo3  = (const float*)d_in[22];
    const float* bo3  = (const float*)d_in[23];
    float* out = (float*)d_out;
    (void)in_sizes; (void)n_in; (void)out_size; (void)ws_size;

    char* ws = (char*)d_ws;
    size_t off = 0;
    f16*   AcatT  = (f16*)(ws + off);   off += (size_t)3072*512*2;
    float* A2     = (float*)(ws + off); off += (size_t)3*500*500*4;
    f16*   WgF1   = (f16*)(ws + off);   off += (size_t)256*448*2;
    f16*   WgF2   = (f16*)(ws + off);   off += (size_t)256*448*2;
    f16*   WgF3   = (f16*)(ws + off);   off += (size_t)256*448*2;
    f16*   WoF1   = (f16*)(ws + off);   off += (size_t)64*64*2;
    f16*   WoF2   = (f16*)(ws + off);   off += (size_t)64*64*2;
    f16*   comb_cv= (f16*)(ws + off);   off += (size_t)2048*512*2;
    f16*   ccv0   = (f16*)(ws + off);   off += (size_t)192*512*2;
    f16*   featsT = (f16*)(ws + off);   off += (size_t)NB*512*448*2;
    f16*   f0T    = (f16*)(ws + off);   off += (size_t)NB*512*42*2;
    float* XE     = (float*)(ws + off); off += (size_t)NT*NB*512*6*4;
    float* hs0T   = (float*)(ws + off); off += (size_t)NT*NB*512*6*4;
    f16*   hs1T   = (f16*)(ws + off);   off += (size_t)NT*NB*512*64*2;
    f16*   hT     = (f16*)(ws + off);   off += (size_t)NB*512*64*2;
    float* cstT   = (float*)(ws + off); off += (size_t)NB*512*64*4;
    float* cst0   = (float*)(ws + off); off += (size_t)NB*500*6*4;
    f16*   Xbuf   = (f16*)(ws + off);   off += (size_t)NT*NB*512*64*2;
    f16*   X3     = (f16*)(ws + off);   off += (size_t)NB*512*64*2;
    float* mean0  = (float*)(ws + off); off += 8192;
    float* se0    = (float*)(ws + off); off += 8192;
    float* mean1  = (float*)(ws + off); off += 8192;
    float* se1    = (float*)(ws + off); off += 8192;
    int*   bar    = (int*)(ws + off);   off += 512;

    const size_t sliceH = (size_t)NB*512*64;

    // ---- prep ----
    k_zero<<<1, 128, 0, stream>>>(bar);
    k_a2  <<<dim3(8, 8, 3), 256, 0, stream>>>(sup, A2);
    k_acat<<<(3072*512 + 255)/256, 256, 0, stream>>>(sup, A2, AcatT);
    k_f2h <<<(256*448 + 255)/256, 256, 0, stream>>>(Wg1, WgF1, 256*448);
    k_f2h <<<(256*448 + 255)/256, 256, 0, stream>>>(Wg2, WgF2, 256*448);
    k_f2h <<<(256*448 + 255)/256, 256, 0, stream>>>(Wg3, WgF3, 256*448);
    k_f2h <<<16, 256, 0, stream>>>(Wo1, WoF1, 64*64);
    k_f2h <<<16, 256, 0, stream>>>(Wo2, WoF2, 64*64);
    k_xe  <<<(NT*NB*512)/256, 256, 0, stream>>>(x, wt, Wemb, XE);

    // ---- layer 0 (persistent) ----
    k_seed0<<<(NB*512)/256, 256, 0, stream>>>(XE, f0T, ccv0);
    k_l0<<<256, 256, 0, stream>>>(AcatT, ccv0, f0T, Wg0, bg0, cst0, hs0T, XE,
                                  bar + 0, bar + 16);
    k_mean0<<<NB, 256, 0, stream>>>(hs0T, mean0);
    k_se   <<<NB, 64, 0, stream>>>(mean0, Wo0, bo0, 6, Wa0, Wb0, se0);

    // ---- layer 1 (persistent) ----
    k_xproj1<<<(NT*NB*512*64)/256, 256, 0, stream>>>(hs0T, Wo0, bo0, se0, Xbuf, NT*NB*512*64);
    k_seed <<<dim3(8, NB), 256, 0, stream>>>(Xbuf, featsT, comb_cv);
    k_big<<<256, 256, 0, stream>>>(AcatT, WgF1, bg1, cstT,
                                   Xbuf, (long)sliceH,
                                   hs1T, (long)sliceH, 0,
                                   nullptr, nullptr, nullptr,
                                   featsT, comb_cv, bar + 32, bar + 48);
    k_mean1<<<dim3(8, NB), 256, 0, stream>>>(hs1T, mean1);
    k_se   <<<NB, 64, 0, stream>>>(mean1, Wo1, bo1, 64, Wa1, Wb1, se1);

    // ---- layer 2 (persistent) ----
    k_xprojm<<<(NT*NB*512)/128, 256, 0, stream>>>(hs1T, WoF1, bo1, se1, Xbuf);
    k_seed <<<dim3(8, NB), 256, 0, stream>>>(Xbuf, featsT, comb_cv);
    k_big<<<256, 256, 0, stream>>>(AcatT, WgF2, bg2, cstT,
                                   Xbuf, (long)sliceH,
                                   hT, 0L, 1,
                                   nullptr, nullptr, nullptr,
                                   featsT, comb_cv, bar + 64, bar + 80);

    // ---- layer 3 (persistent, fixed input x3 = Wo2.h2_last + bo2) ----
    k_xprojm<<<(NB*512)/128, 256, 0, stream>>>(hT, WoF2, bo2, nullptr, X3);
    k_seed <<<dim3(8, NB), 256, 0, stream>>>(X3, featsT, comb_cv);
    k_big<<<256, 256, 0, stream>>>(AcatT, WgF3, bg3, cstT,
                                   X3, 0L,
                                   nullptr, 0L, 0,
                                   Wo3, bo3, out,
                                   featsT, comb_cv, bar + 96, bar + 112);
}

// Round 6
// 5284.003 us; speedup vs baseline: 4.6072x; 4.6072x over previous
//
#include <hip/hip_runtime.h>
#include <math.h>

#define NV 500
#define NB 32
#define NT 24
#define NH 64

typedef _Float16 f16;
typedef _Float16 f16x8 __attribute__((ext_vector_type(8)));
typedef _Float16 f16x4 __attribute__((ext_vector_type(4)));
typedef float    f32x4 __attribute__((ext_vector_type(4)));

__device__ __forceinline__ float sigm(float x){ return 1.f/(1.f+expf(-x)); }

// feats LDS index: [v][g] row 448 f16, symmetric XOR swizzle (write & read pass TRUE g)
#define FID(v,g) ((((v)*448) + (g)) ^ (((v)&7)<<3))

// ======================= prep kernels =======================
// tiled f32 GEMM: A2[s] = A[s] @ A[s]; grid (8,8,3), 64x64 tile  [validated R4]
__global__ __launch_bounds__(256)
void k_a2(const float* __restrict__ A, float* __restrict__ A2)
{
    __shared__ float tA[64][33];
    __shared__ float tB[32][65];
    const int s = blockIdx.z;
    const int r0 = blockIdx.y*64, w0 = blockIdx.x*64;
    const float* As = A + (size_t)s*500*500;
    const int tid = threadIdx.x;
    const int ty = tid>>4, tx = tid&15;
    float acc[4][4] = {};
    for (int k0 = 0; k0 < 500; k0 += 32) {
        __syncthreads();
        for (int e = tid; e < 64*32; e += 256) {
            int r = e>>5, kk = e&31;
            float v = 0.f;
            if (r0+r < 500 && k0+kk < 500) v = As[(size_t)(r0+r)*500 + k0+kk];
            tA[r][kk] = v;
        }
        for (int e = tid; e < 32*64; e += 256) {
            int kk = e>>6, ww = e&63;
            float v = 0.f;
            if (k0+kk < 500 && w0+ww < 500) v = As[(size_t)(k0+kk)*500 + w0+ww];
            tB[kk][ww] = v;
        }
        __syncthreads();
        #pragma unroll 8
        for (int kk = 0; kk < 32; kk++) {
            float a0=tA[ty][kk], a1=tA[ty+16][kk], a2=tA[ty+32][kk], a3=tA[ty+48][kk];
            float b0=tB[kk][tx], b1=tB[kk][tx+16], b2=tB[kk][tx+32], b3=tB[kk][tx+48];
            acc[0][0]+=a0*b0; acc[0][1]+=a0*b1; acc[0][2]+=a0*b2; acc[0][3]+=a0*b3;
            acc[1][0]+=a1*b0; acc[1][1]+=a1*b1; acc[1][2]+=a1*b2; acc[1][3]+=a1*b3;
            acc[2][0]+=a2*b0; acc[2][1]+=a2*b1; acc[2][2]+=a2*b2; acc[2][3]+=a2*b3;
            acc[3][0]+=a3*b0; acc[3][1]+=a3*b1; acc[3][2]+=a3*b2; acc[3][3]+=a3*b3;
        }
    }
    #pragma unroll
    for (int i=0;i<4;i++) {
        int r = r0 + ty + 16*i;
        if (r >= 500) continue;
        #pragma unroll
        for (int j=0;j<4;j++) {
            int ww = w0 + tx + 16*j;
            if (ww < 500) A2[((size_t)s*500 + r)*500 + ww] = acc[i][j];
        }
    }
}

__global__ void k_acat(const float* __restrict__ A, const float* __restrict__ A2,
                       f16* __restrict__ AcatT)
{
    int idx = blockIdx.x*256 + threadIdx.x;
    if (idx >= 3072*512) return;
    int k = idx & 511;     // v
    int n = idx >> 9;      // j*512 + w
    int j = n >> 9, wv = n & 511;
    float val = 0.f;
    if (k < 500 && wv < 500) {
        int s = j >> 1;
        const float* M = (j & 1) ? A2 : A;
        val = M[((size_t)s*500 + k)*500 + wv];
    }
    AcatT[idx] = (f16)val;
}

__global__ void k_f2h(const float* __restrict__ src, f16* __restrict__ dst, int n)
{
    int idx = blockIdx.x*256 + threadIdx.x;
    if (idx < n) dst[idx] = (f16)src[idx];
}

// ======================= MFMA diffusion GEMM (layer 0 only) =======================
__global__ __launch_bounds__(256)
void k_diff(const f16* __restrict__ Acv, const f16* __restrict__ Bt,
            f16* __restrict__ fout, int Mtot, int C, int G)
{
    __shared__ f16 lA[128*32];
    __shared__ f16 lB[128*32];
    const int tid = threadIdx.x;
    const int n0 = blockIdx.x*128, m0 = blockIdx.y*128;
    const int r0 = tid>>2, c0 = tid&3;
    const int swz0 = r0*32 + ((c0 ^ ((r0>>1)&3))<<3);
    const int swz1 = swz0 + 64*32;
    int mA0 = m0 + r0;      if (mA0 > Mtot-1) mA0 = Mtot-1;
    int mA1 = m0 + r0 + 64; if (mA1 > Mtot-1) mA1 = Mtot-1;
    const f16* gA0 = Acv + (size_t)mA0*512 + c0*8;
    const f16* gA1 = Acv + (size_t)mA1*512 + c0*8;
    const f16* gB0 = Bt + (size_t)(n0+r0)*512 + c0*8;
    const f16* gB1 = Bt + (size_t)(n0+r0+64)*512 + c0*8;

    const int w = tid>>6, lane = tid&63;
    const int wr = (w>>1)<<6, wc = (w&1)<<6;
    const int fm = lane&15, fk = lane>>4;
    const int fch = (fk ^ ((fm>>1)&3))<<3;

    f32x4 acc[4][4];
    #pragma unroll
    for (int i=0;i<4;i++)
        #pragma unroll
        for (int j=0;j<4;j++) acc[i][j] = (f32x4){0.f,0.f,0.f,0.f};

    f32x4 ra0 = *(const f32x4*)gA0, ra1 = *(const f32x4*)gA1;
    f32x4 rb0 = *(const f32x4*)gB0, rb1 = *(const f32x4*)gB1;

    for (int ks = 0; ks < 16; ks++) {
        __syncthreads();
        *(f32x4*)(lA + swz0) = ra0;  *(f32x4*)(lA + swz1) = ra1;
        *(f32x4*)(lB + swz0) = rb0;  *(f32x4*)(lB + swz1) = rb1;
        if (ks < 15) {
            int o = (ks+1)*32;
            ra0 = *(const f32x4*)(gA0 + o); ra1 = *(const f32x4*)(gA1 + o);
            rb0 = *(const f32x4*)(gB0 + o); rb1 = *(const f32x4*)(gB1 + o);
        }
        __syncthreads();
        f16x8 af[4], bf[4];
        #pragma unroll
        for (int i=0;i<4;i++) af[i] = *(const f16x8*)(lA + (wr + i*16 + fm)*32 + fch);
        #pragma unroll
        for (int j=0;j<4;j++) bf[j] = *(const f16x8*)(lB + (wc + j*16 + fm)*32 + fch);
        #pragma unroll
        for (int i=0;i<4;i++)
            #pragma unroll
            for (int j=0;j<4;j++)
                acc[i][j] = __builtin_amdgcn_mfma_f32_16x16x32_f16(af[i], bf[j], acc[i][j], 0, 0, 0);
    }

    #pragma unroll
    for (int j=0;j<4;j++) {
        int col = n0 + wc + j*16 + fm;
        int jb = col >> 9, wv = col & 511;
        if (wv >= 500) continue;
        #pragma unroll
        for (int i=0;i<4;i++) {
            int mb = m0 + wr + i*16 + fk*4;
            #pragma unroll
            for (int r=0;r<4;r++) {
                int m = mb + r;
                if (m < Mtot) {
                    int b = m / C, c = m - b*C;
                    fout[((size_t)b*512 + wv)*G + C + jb*C + c] = (f16)acc[i][j][r];
                }
            }
        }
    }
}

// ======================= fused per-step kernel (layers 1-3) =======================
// Block (vt, b): 64 vertices of batch b. Phase A: diffusion feats[64v][448] built in LDS
// (6 GEMMs 64x64x512 + comb copy). Phase B: gates GEMM 64v x 256o x 448 (A from LDS).
// Phase C: LSTM + h save + optional L3 out-proj + next-step comb (both layouts, dbuf'd).
__global__ __launch_bounds__(256)
void k_step(const f16* __restrict__ AcatT, const f16* __restrict__ ccv,
            const f16* __restrict__ combV, const f16* __restrict__ Wg,
            const float* __restrict__ bg, float* __restrict__ cst,
            const f16* __restrict__ Xn, f16* __restrict__ hsave,
            const float* __restrict__ Wo3, const float* __restrict__ bo3,
            float* __restrict__ out, int t,
            f16* __restrict__ ccv_out, f16* __restrict__ combV_out,
            int first, int writecomb)
{
    __shared__ __align__(16) f16 SM[64*448 + 4096];   // feats (57344B) + staging (8192B)
    f16* feats = SM;
    f16* stg   = SM + 64*448;
    f16* lA = stg;            // phase A: 64x32
    f16* lB = stg + 2048;     // phase A: 64x32

    const int tid = threadIdx.x;
    const int vt = blockIdx.x, b = blockIdx.y;
    const int w = tid>>6, lane = tid&63;
    const int fm = lane&15, fk = lane>>4;
    const int fch = (fk ^ ((fm>>1)&3))<<3;
    const int r0 = tid>>2, c0 = tid&3;
    const int swz = r0*32 + ((c0 ^ ((r0>>1)&3))<<3);
    const int wrA = (w>>1)<<5;   // v-offset (0/32)
    const int wcA = (w&1)<<5;    // phase A c-offset (0/32)
    const int wcB = (w&1)<<6;    // phase B o-offset (0/64)

    // ---- phase A0: comb part of feats (g 0..63) from combV ----
    {
        int chunk = tid;
        #pragma unroll
        for (int pass=0; pass<2; pass++, chunk += 256) {
            int v = chunk>>3, c8 = (chunk&7)<<3;
            f32x4 d = *(const f32x4*)(combV + ((size_t)b*512 + vt*64 + v)*64 + c8);
            *(f32x4*)(feats + FID(v, c8)) = d;
        }
    }

    // ---- phase A: 6 diffusion GEMMs 64v x 64c x 512 ----
    for (int jj = 0; jj < 6; jj++) {
        const f16* gA = AcatT + ((size_t)(jj*512 + vt*64 + r0))*512 + c0*8;
        const f16* gB = ccv + ((size_t)b*64 + r0)*512 + c0*8;
        f32x4 ra = *(const f32x4*)gA;
        f32x4 rb = *(const f32x4*)gB;
        f32x4 acc[2][2];
        #pragma unroll
        for (int i=0;i<2;i++)
            #pragma unroll
            for (int j=0;j<2;j++) acc[i][j] = (f32x4){0.f,0.f,0.f,0.f};
        for (int ks = 0; ks < 16; ks++) {
            __syncthreads();
            *(f32x4*)(lA + swz) = ra;
            *(f32x4*)(lB + swz) = rb;
            if (ks < 15) {
                int o = (ks+1)*32;
                ra = *(const f32x4*)(gA + o);
                rb = *(const f32x4*)(gB + o);
            }
            __syncthreads();
            f16x8 af[2], bf[2];
            #pragma unroll
            for (int i=0;i<2;i++) af[i] = *(const f16x8*)(lA + (wrA + i*16 + fm)*32 + fch);
            #pragma unroll
            for (int j=0;j<2;j++) bf[j] = *(const f16x8*)(lB + (wcA + j*16 + fm)*32 + fch);
            #pragma unroll
            for (int i=0;i<2;i++)
                #pragma unroll
                for (int j=0;j<2;j++)
                    acc[i][j] = __builtin_amdgcn_mfma_f32_16x16x32_f16(af[i], bf[j], acc[i][j], 0, 0, 0);
        }
        #pragma unroll
        for (int i=0;i<2;i++)
            #pragma unroll
            for (int j=0;j<2;j++)
                #pragma unroll
                for (int rr=0;rr<4;rr++) {
                    int v = wrA + i*16 + (fk<<2) + rr;
                    int g = 64 + jj*64 + wcA + j*16 + fm;
                    feats[FID(v, g)] = (f16)acc[i][j][rr];
                }
    }
    __syncthreads();   // feats complete

    // ---- phase B: gates GEMM, two o-halves of 128 ----
    // A-frags from feats: FID is symmetric, so pass TRUE k index (fk<<3), NOT fch.
    f32x4 acch[2][2][4];
    #pragma unroll
    for (int h = 0; h < 2; h++) {
        const f16* gW0 = Wg + ((size_t)(h*128 + r0))*448 + c0*8;
        const f16* gW1 = gW0 + (size_t)64*448;
        f32x4 rw0 = *(const f32x4*)gW0;
        f32x4 rw1 = *(const f32x4*)gW1;
        f32x4 acc[2][4];
        #pragma unroll
        for (int i=0;i<2;i++)
            #pragma unroll
            for (int j=0;j<4;j++) acc[i][j] = (f32x4){0.f,0.f,0.f,0.f};
        for (int ks = 0; ks < 14; ks++) {
            __syncthreads();
            *(f32x4*)(stg + swz) = rw0;
            *(f32x4*)(stg + 64*32 + swz) = rw1;
            if (ks < 13) {
                int o = (ks+1)*32;
                rw0 = *(const f32x4*)(gW0 + o);
                rw1 = *(const f32x4*)(gW1 + o);
            }
            __syncthreads();
            f16x8 af[2], bf[4];
            #pragma unroll
            for (int i=0;i<2;i++) {
                int m = wrA + i*16 + fm;
                af[i] = *(const f16x8*)(feats + FID(m, ks*32 + (fk<<3)));
            }
            #pragma unroll
            for (int j=0;j<4;j++) bf[j] = *(const f16x8*)(stg + (wcB + j*16 + fm)*32 + fch);
            #pragma unroll
            for (int i=0;i<2;i++)
                #pragma unroll
                for (int j=0;j<4;j++)
                    acc[i][j] = __builtin_amdgcn_mfma_f32_16x16x32_f16(af[i], bf[j], acc[i][j], 0, 0, 0);
        }
        #pragma unroll
        for (int i=0;i<2;i++)
            #pragma unroll
            for (int j=0;j<4;j++) acch[h][i][j] = acc[i][j];
    }
    __syncthreads();   // all feats reads done; overlay ExF

    // ---- exchange: ExF[q][v][c] f16 (32KB overlay at SM base) ----
    f16* ExF = SM;
    #pragma unroll
    for (int h=0;h<2;h++) {
        const int q = h*2 + (w&1);
        #pragma unroll
        for (int i=0;i<2;i++)
            #pragma unroll
            for (int j=0;j<4;j++)
                #pragma unroll
                for (int rr=0;rr<4;rr++) {
                    int v = wrA + i*16 + (fk<<2) + rr;
                    int c = j*16 + fm;
                    ExF[((((q<<6)+v)<<6) + c) ^ ((v&7)<<3)] = (f16)acch[h][i][j][rr];
                }
    }
    __syncthreads();

    // ---- LSTM pointwise ----
    const int vl = tid>>2, p = tid&3;
    const int v = vt*64 + vl;
    const size_t row = (size_t)b*512 + v;
    alignas(16) f16 gq[4][16];
    #pragma unroll
    for (int q=0;q<4;q++) {
        int base = (((q<<6)+vl)<<6) + (p<<4);
        *(f32x4*)&gq[q][0] = *(const f32x4*)(ExF + (base ^ ((vl&7)<<3)));
        *(f32x4*)&gq[q][8] = *(const f32x4*)(ExF + ((base+8) ^ ((vl&7)<<3)));
    }
    float hy[16];
    float* cp = cst + row*64 + (p<<4);
    #pragma unroll
    for (int k4=0;k4<4;k4++) {
        f32x4 cx4 = first ? (f32x4){0.f,0.f,0.f,0.f} : *(const f32x4*)(cp + k4*4);
        f32x4 cy4;
        #pragma unroll
        for (int e=0;e<4;e++) {
            int kk = k4*4+e, c = (p<<4) + kk;
            float gi = (float)gq[0][kk] + bg[c];
            float gf = (float)gq[1][kk] + bg[64+c];
            float gcv= (float)gq[2][kk] + bg[128+c];
            float go = (float)gq[3][kk] + bg[192+c];
            float cy = sigm(gf)*cx4[e] + sigm(gi)*gcv;
            cy4[e] = cy;
            hy[kk] = sigm(go)*tanhf(cy);
        }
        *(f32x4*)(cp + k4*4) = cy4;
    }

    if (hsave) {
        alignas(16) f16 tmp[16];
        #pragma unroll
        for (int k=0;k<16;k++) tmp[k] = (f16)hy[k];
        f16* hp = hsave + row*64 + (p<<4);
        *(f32x4*)hp = *(f32x4*)tmp;
        *(f32x4*)(hp+8) = *(f32x4*)(tmp+8);
    }

    if (out) {
        float r0s = 0.f, r1s = 0.f;
        #pragma unroll
        for (int k=0;k<16;k++){ r0s += Wo3[(p<<4)+k]*hy[k]; r1s += Wo3[64+(p<<4)+k]*hy[k]; }
        r0s += __shfl_xor(r0s, 1, 64); r0s += __shfl_xor(r0s, 2, 64);
        r1s += __shfl_xor(r1s, 1, 64); r1s += __shfl_xor(r1s, 2, 64);
        if (p == 0 && v < 500) {
            out[((size_t)(b*2+0)*500 + v)*24 + t] = r0s + bo3[0];
            out[((size_t)(b*2+1)*500 + v)*24 + t] = r1s + bo3[1];
        }
    }

    // ---- phase C: next-step comb (both layouts) ----
    if (writecomb) {
        f16* combS = SM + 16384;   // [64][68] overlay, disjoint from ExF
        alignas(16) f16 c16[16];
        if (v < 500) {
            const f16* xp = Xn + row*64 + (p<<4);
            alignas(16) f16 xv[16];
            *(f32x4*)xv = *(const f32x4*)xp;
            *(f32x4*)(xv+8) = *(const f32x4*)(xp+8);
            #pragma unroll
            for (int k=0;k<16;k++) c16[k] = (f16)((float)xv[k] + hy[k]);
        } else {
            #pragma unroll
            for (int k=0;k<16;k++) c16[k] = (f16)0.f;
        }
        *(f32x4*)(combV_out + row*64 + (p<<4)) = *(f32x4*)c16;
        *(f32x4*)(combV_out + row*64 + (p<<4) + 8) = *(f32x4*)(c16+8);
        #pragma unroll
        for (int k=0;k<16;k++) combS[vl*68 + (p<<4) + k] = c16[k];
        __syncthreads();
        const int cc = tid>>2, jj2 = tid&3;
        alignas(16) f16 tmp[16];
        #pragma unroll
        for (int k=0;k<16;k++) tmp[k] = combS[(jj2*16+k)*68 + cc];
        f16* dst = ccv_out + ((size_t)b*64 + cc)*512 + vt*64 + jj2*16;
        *(f32x4*)dst = *(f32x4*)tmp;
        *(f32x4*)(dst+8) = *(f32x4*)(tmp+8);
    }
}

// ======================= seed comb for t=0 (big layers) =======================
__global__ __launch_bounds__(256)
void k_seed(const f16* __restrict__ X0, f16* __restrict__ ccv, f16* __restrict__ combV)
{
    __shared__ f16 combS[64*68];
    const int b = blockIdx.y, v0 = blockIdx.x*64;
    const int tid = threadIdx.x, vl = tid>>2, p = tid&3;
    const int v = v0 + vl;
    const size_t row = (size_t)b*512 + v;
    alignas(16) f16 c16[16];
    if (v < 500) {
        const f16* xp = X0 + row*64 + p*16;
        *(f32x4*)c16 = *(const f32x4*)xp;
        *(f32x4*)(c16+8) = *(const f32x4*)(xp+8);
    } else {
        #pragma unroll
        for (int k=0;k<16;k++) c16[k] = (f16)0.f;
    }
    *(f32x4*)(combV + row*64 + p*16) = *(f32x4*)c16;
    *(f32x4*)(combV + row*64 + p*16 + 8) = *(f32x4*)(c16+8);
    #pragma unroll
    for (int k=0;k<16;k++) combS[vl*68 + p*16 + k] = c16[k];
    __syncthreads();
    const int c = tid>>2, j = tid&3;
    alignas(16) f16 tmp[16];
    #pragma unroll
    for (int k=0;k<16;k++) tmp[k] = combS[(j*16+k)*68 + c];
    f16* dst = ccv + ((size_t)b*64 + c)*512 + v0 + j*16;
    *(f32x4*)dst = *(f32x4*)tmp;
    *(f32x4*)(dst+8) = *(f32x4*)(tmp+8);
}

// ======================= MFMA input projection (Cin=64, f16 src) =======================
__global__ __launch_bounds__(256)
void k_xprojm(const f16* __restrict__ src, const f16* __restrict__ WoF,
              const float* __restrict__ bo, const float* __restrict__ se,
              f16* __restrict__ X)
{
    __shared__ f16 lA[128*64];
    __shared__ f16 lB[64*64];
    const int tid = threadIdx.x;
    const size_t m0 = (size_t)blockIdx.x*128;
    const int r0 = tid>>2, c0 = tid&3;
    const int swz = r0*32 + ((c0 ^ ((r0>>1)&3))<<3);
    const f16* gA0 = src + (m0 + r0)*64 + c0*8;
    const f16* gA1 = gA0 + 64*64;
    const f16* gB  = WoF + r0*64 + c0*8;

    *(f32x4*)(lA + swz)               = *(const f32x4*)gA0;
    *(f32x4*)(lA + 2048 + swz)        = *(const f32x4*)gA1;
    *(f32x4*)(lA + 4096 + swz)        = *(const f32x4*)(gA0 + 32);
    *(f32x4*)(lA + 6144 + swz)        = *(const f32x4*)(gA1 + 32);
    *(f32x4*)(lB + swz)               = *(const f32x4*)gB;
    *(f32x4*)(lB + 2048 + swz)        = *(const f32x4*)(gB + 32);
    __syncthreads();

    const int w = tid>>6, lane = tid&63;
    const int wr = w<<5;
    const int fm = lane&15, fk = lane>>4;
    const int fch = (fk ^ ((fm>>1)&3))<<3;

    f32x4 acc[2][4];
    #pragma unroll
    for (int i=0;i<2;i++)
        #pragma unroll
        for (int j=0;j<4;j++) acc[i][j] = (f32x4){0.f,0.f,0.f,0.f};

    #pragma unroll
    for (int ks=0; ks<2; ks++) {
        f16x8 af[2], bf[4];
        #pragma unroll
        for (int i=0;i<2;i++) af[i] = *(const f16x8*)(lA + ks*4096 + (wr + i*16 + fm)*32 + fch);
        #pragma unroll
        for (int j=0;j<4;j++) bf[j] = *(const f16x8*)(lB + ks*2048 + (j*16 + fm)*32 + fch);
        #pragma unroll
        for (int i=0;i<2;i++)
            #pragma unroll
            for (int j=0;j<4;j++)
                acc[i][j] = __builtin_amdgcn_mfma_f32_16x16x32_f16(af[i], bf[j], acc[i][j], 0, 0, 0);
    }
    __syncthreads();

    const int bb = (int)((m0 >> 9) & 31);
    #pragma unroll
    for (int j=0;j<4;j++) {
        const int c = (j<<4) + fm;
        const float bias = bo[c];
        const float sf = se ? se[bb*64 + c] : 1.f;
        #pragma unroll
        for (int i=0;i<2;i++) {
            const int rbase = wr + i*16 + (fk<<2);
            #pragma unroll
            for (int r=0;r<4;r++)
                lA[(rbase + r)*64 + c] = (f16)(sf*(acc[i][j][r] + bias));
        }
    }
    __syncthreads();
    #pragma unroll
    for (int pass=0; pass<4; pass++) {
        int chunk = pass*256 + tid;
        int row = chunk>>3, off = (chunk&7)<<3;
        *(f32x4*)(X + (m0 + row)*64 + off) = *(const f32x4*)(lA + row*64 + off);
    }
}

// ======================= scalar input projection (Cin=6, f32 src, layer 1) =======================
__global__ void k_xproj1(const float* __restrict__ src, const float* __restrict__ Wo,
                         const float* __restrict__ bo, const float* __restrict__ se,
                         f16* __restrict__ X, int total)
{
    int id = blockIdx.x*256 + threadIdx.x;
    if (id >= total) return;
    int c = id & 63;
    size_t row = (size_t)(id >> 6);
    int b = (int)((row >> 9) & 31);
    const float* sp = src + row*6;
    float a = bo[c];
    #pragma unroll
    for (int j=0;j<6;j++) a += Wo[c*6+j]*sp[j];
    X[id] = (f16)(se[b*64+c]*a);
}

// ======================= layer 0 =======================
__global__ void k_xe(const float* __restrict__ x, const int* __restrict__ wt,
                     const float* __restrict__ Wemb, float* __restrict__ XE)
{
    int id = blockIdx.x*256 + threadIdx.x;
    if (id >= NT*NB*512) return;
    int v = id & 511; int r = id >> 9; int b = r & 31; int t = r >> 5;
    float vals[6] = {0.f,0.f,0.f,0.f,0.f,0.f};
    if (v < 500) {
        vals[0] = x[((size_t)(b*2+0)*500 + v)*24 + t];
        vals[1] = x[((size_t)(b*2+1)*500 + v)*24 + t];
        int wty = wt[((size_t)b*500 + v)*24 + t];
        vals[2] = Wemb[wty*4+0]; vals[3] = Wemb[wty*4+1];
        vals[4] = Wemb[wty*4+2]; vals[5] = Wemb[wty*4+3];
    }
    float* xe = XE + (size_t)id*6;
    #pragma unroll
    for (int c = 0; c < 6; c++) xe[c] = vals[c];
}

__global__ void k_seed0(const float* __restrict__ XE, f16* __restrict__ f0T,
                        f16* __restrict__ ccv0)
{
    int id = blockIdx.x*256 + threadIdx.x;
    if (id >= NB*512) return;
    int v = id & 511, b = id >> 9;
    const float* xe = XE + (size_t)id*6;
    #pragma unroll
    for (int c = 0; c < 6; c++) {
        f16 h = (v < 500) ? (f16)xe[c] : (f16)0.f;
        f0T[(size_t)id*42 + c] = h;
        ccv0[((size_t)b*6 + c)*512 + v] = h;
    }
}

__global__ __launch_bounds__(256)
void k_glstm0(f16* f0T, const float* __restrict__ Wg0,
              const float* __restrict__ bg0, float* __restrict__ cst0,
              float* __restrict__ hs0T, const float* __restrict__ XE,
              f16* __restrict__ ccv0, int t)
{
    __shared__ float WgS[24*42];
    __shared__ float bgS[24];
    int tid = threadIdx.x;
    for (int i = tid; i < 24*42; i += 256) WgS[i] = Wg0[i];
    if (tid < 24) bgS[tid] = bg0[tid];
    __syncthreads();
    int id = blockIdx.x*256 + tid;
    if (id >= NB*500) return;
    int b = id / 500, v = id - b*500;
    const f16* fp = f0T + ((size_t)b*512 + v)*42;
    float fv[42];
    #pragma unroll
    for (int g = 0; g < 42; g++) fv[g] = (float)fp[g];
    float gates[24];
    #pragma unroll
    for (int o = 0; o < 24; o++) {
        float a = bgS[o];
        #pragma unroll
        for (int g = 0; g < 42; g++) a += WgS[o*42+g]*fv[g];
        gates[o] = a;
    }
    size_t hrow = (((size_t)t*NB + b)*512 + v)*6;
    const float* xe = XE + (((size_t)(t+1)*NB + b)*512 + v)*6;   // only read if t<23
    #pragma unroll
    for (int c = 0; c < 6; c++) {
        size_t ci = ((size_t)b*500 + v)*6 + c;
        float cx = t ? cst0[ci] : 0.f;
        float cy = sigm(gates[6+c])*cx + sigm(gates[c])*gates[12+c];
        cst0[ci] = cy;
        float h = sigm(gates[18+c])*tanhf(cy);
        hs0T[hrow + c] = h;
        if (t < 23) {
            float cmb = xe[c] + h;
            f0T[((size_t)b*512 + v)*42 + c] = (f16)cmb;
            ccv0[((size_t)b*6 + c)*512 + v] = (f16)cmb;
        }
    }
}

// ======================= SE path =======================
__global__ void k_mean0(const float* __restrict__ hs0T, float* __restrict__ mean0)
{
    int b = blockIdx.x;
    float acc[6] = {0,0,0,0,0,0};
    for (int i = threadIdx.x; i < 24*500; i += 256) {
        int tt = i/500, v = i - tt*500;
        const float* p = hs0T + (((size_t)tt*NB + b)*512 + v)*6;
        #pragma unroll
        for (int c=0;c<6;c++) acc[c] += p[c];
    }
    __shared__ float red[256];
    for (int c=0;c<6;c++) {
        red[threadIdx.x] = acc[c]; __syncthreads();
        for (int s=128;s>0;s>>=1) { if (threadIdx.x<s) red[threadIdx.x]+=red[threadIdx.x+s]; __syncthreads(); }
        if (threadIdx.x==0) mean0[b*6+c] = red[0]/12000.f;
        __syncthreads();
    }
}

__global__ void k_mean1(const f16* __restrict__ hs1T, float* __restrict__ mean1)
{
    int cg = blockIdx.x, b = blockIdx.y;
    float acc[8] = {0,0,0,0,0,0,0,0};
    for (int i = threadIdx.x; i < 24*500; i += 256) {
        int tt = i/500, v = i - tt*500;
        const f16* p = hs1T + (((size_t)tt*NB + b)*512 + v)*64 + cg*8;
        #pragma unroll
        for (int c=0;c<8;c++) acc[c] += (float)p[c];
    }
    __shared__ float red[256];
    for (int c=0;c<8;c++) {
        red[threadIdx.x] = acc[c]; __syncthreads();
        for (int s=128;s>0;s>>=1) { if (threadIdx.x<s) red[threadIdx.x]+=red[threadIdx.x+s]; __syncthreads(); }
        if (threadIdx.x==0) mean1[b*64 + cg*8 + c] = red[0]/12000.f;
        __syncthreads();
    }
}

__global__ void k_se(const float* __restrict__ meanhs, const float* __restrict__ Wo,
                     const float* __restrict__ bo, int Cin,
                     const float* __restrict__ Wa, const float* __restrict__ Wb,
                     float* __restrict__ se)
{
    int b = blockIdx.x; int c = threadIdx.x;
    __shared__ float y[64]; __shared__ float a[4];
    float acc = bo[c];
    for (int j = 0; j < Cin; j++) acc += Wo[(size_t)c*Cin + j] * meanhs[b*Cin + j];
    y[c] = acc;
    __syncthreads();
    if (c < 4) {
        float s = 0.f;
        for (int j = 0; j < 64; j++) s += Wa[c*64 + j] * y[j];
        a[c] = fmaxf(s, 0.f);
    }
    __syncthreads();
    float s = 0.f;
    #pragma unroll
    for (int j = 0; j < 4; j++) s += Wb[c*4 + j] * a[j];
    se[b*64 + c] = 1.f/(1.f + expf(-s));
}

// ======================= host launch =======================
extern "C" void kernel_launch(void* const* d_in, const int* in_sizes, int n_in,
                              void* d_out, int out_size, void* d_ws, size_t ws_size,
                              hipStream_t stream)
{
    const float* x    = (const float*)d_in[0];
    const float* sup  = (const float*)d_in[1];
    const int*   wt   = (const int*)  d_in[2];
    const float* Wemb = (const float*)d_in[3];
    const float* Wg0  = (const float*)d_in[4];
    const float* bg0  = (const float*)d_in[5];
    const float* Wo0  = (const float*)d_in[6];
    const float* bo0  = (const float*)d_in[7];
    const float* Wa0  = (const float*)d_in[8];
    const float* Wb0  = (const float*)d_in[9];
    const float* Wg1  = (const float*)d_in[10];
    const float* bg1  = (const float*)d_in[11];
    const float* Wo1  = (const float*)d_in[12];
    const float* bo1  = (const float*)d_in[13];
    const float* Wa1  = (const float*)d_in[14];
    const float* Wb1  = (const float*)d_in[15];
    const float* Wg2  = (const float*)d_in[16];
    const float* bg2  = (const float*)d_in[17];
    const float* Wo2  = (const float*)d_in[18];
    const float* bo2  = (const float*)d_in[19];
    const float* Wg3  = (const float*)d_in[20];
    const float* bg3  = (const float*)d_in[21];
    const float* Wo3  = (const float*)d_in[22];
    const float* bo3  = (const float*)d_in[23];
    float* out = (float*)d_out;
    (void)in_sizes; (void)n_in; (void)out_size; (void)ws_size;

    char* ws = (char*)d_ws;
    size_t off = 0;
    f16*   AcatT  = (f16*)(ws + off);   off += (size_t)3072*512*2;
    float* A2     = (float*)(ws + off); off += (size_t)3*500*500*4;
    f16*   WgF1   = (f16*)(ws + off);   off += (size_t)256*448*2;
    f16*   WgF2   = (f16*)(ws + off);   off += (size_t)256*448*2;
    f16*   WgF3   = (f16*)(ws + off);   off += (size_t)256*448*2;
    f16*   WoF1   = (f16*)(ws + off);   off += (size_t)64*64*2;
    f16*   WoF2   = (f16*)(ws + off);   off += (size_t)64*64*2;
    f16*   ccvP0  = (f16*)(ws + off);   off += (size_t)2048*512*2;
    f16*   ccvP1  = (f16*)(ws + off);   off += (size_t)2048*512*2;
    f16*   combV0 = (f16*)(ws + off);   off += (size_t)NB*512*64*2;
    f16*   combV1 = (f16*)(ws + off);   off += (size_t)NB*512*64*2;
    f16*   ccv0   = (f16*)(ws + off);   off += (size_t)192*512*2;
    f16*   f0T    = (f16*)(ws + off);   off += (size_t)NB*512*42*2;
    float* XE     = (float*)(ws + off); off += (size_t)NT*NB*512*6*4;
    float* hs0T   = (float*)(ws + off); off += (size_t)NT*NB*512*6*4;
    f16*   hs1T   = (f16*)(ws + off);   off += (size_t)NT*NB*512*64*2;
    f16*   hT     = (f16*)(ws + off);   off += (size_t)NB*512*64*2;
    float* cstT   = (float*)(ws + off); off += (size_t)NB*512*64*4;
    float* cst0   = (float*)(ws + off); off += (size_t)NB*500*6*4;
    f16*   Xbuf   = (f16*)(ws + off);   off += (size_t)NT*NB*512*64*2;
    f16*   X3     = (f16*)(ws + off);   off += (size_t)NB*512*64*2;
    float* mean0  = (float*)(ws + off); off += 8192;
    float* se0    = (float*)(ws + off); off += 8192;
    float* mean1  = (float*)(ws + off); off += 8192;
    float* se1    = (float*)(ws + off); off += 8192;

    const size_t sliceH = (size_t)NB*512*64;

    // ---- prep ----
    k_a2  <<<dim3(8, 8, 3), 256, 0, stream>>>(sup, A2);
    k_acat<<<(3072*512 + 255)/256, 256, 0, stream>>>(sup, A2, AcatT);
    k_f2h <<<(256*448 + 255)/256, 256, 0, stream>>>(Wg1, WgF1, 256*448);
    k_f2h <<<(256*448 + 255)/256, 256, 0, stream>>>(Wg2, WgF2, 256*448);
    k_f2h <<<(256*448 + 255)/256, 256, 0, stream>>>(Wg3, WgF3, 256*448);
    k_f2h <<<16, 256, 0, stream>>>(Wo1, WoF1, 64*64);
    k_f2h <<<16, 256, 0, stream>>>(Wo2, WoF2, 64*64);
    k_xe  <<<(NT*NB*512)/256, 256, 0, stream>>>(x, wt, Wemb, XE);

    // ---- layer 0 ----
    k_seed0<<<(NB*512)/256, 256, 0, stream>>>(XE, f0T, ccv0);
    for (int t = 0; t < NT; t++) {
        k_diff  <<<dim3(24, 2), 256, 0, stream>>>(ccv0, AcatT, f0T, 192, 6, 42);
        k_glstm0<<<(NB*500 + 255)/256, 256, 0, stream>>>(f0T, Wg0, bg0, cst0, hs0T, XE, ccv0, t);
    }
    k_mean0<<<NB, 256, 0, stream>>>(hs0T, mean0);
    k_se   <<<NB, 64, 0, stream>>>(mean0, Wo0, bo0, 6, Wa0, Wb0, se0);

    // ---- layer 1 ----
    k_xproj1<<<(NT*NB*512*64)/256, 256, 0, stream>>>(hs0T, Wo0, bo0, se0, Xbuf, NT*NB*512*64);
    k_seed <<<dim3(8, NB), 256, 0, stream>>>(Xbuf, ccvP0, combV0);
    for (int t = 0; t < NT; t++) {
        f16* ccvR  = (t & 1) ? ccvP1  : ccvP0;
        f16* ccvW  = (t & 1) ? ccvP0  : ccvP1;
        f16* cvR   = (t & 1) ? combV1 : combV0;
        f16* cvW   = (t & 1) ? combV0 : combV1;
        k_step<<<dim3(8, NB), 256, 0, stream>>>(AcatT, ccvR, cvR, WgF1, bg1, cstT,
                 (t < 23) ? Xbuf + (size_t)(t+1)*sliceH : (const f16*)nullptr,
                 hs1T + (size_t)t*sliceH, nullptr, nullptr, nullptr, t,
                 ccvW, cvW, t == 0, t < 23);
    }
    k_mean1<<<dim3(8, NB), 256, 0, stream>>>(hs1T, mean1);
    k_se   <<<NB, 64, 0, stream>>>(mean1, Wo1, bo1, 64, Wa1, Wb1, se1);

    // ---- layer 2 ----
    k_xprojm<<<(NT*NB*512)/128, 256, 0, stream>>>(hs1T, WoF1, bo1, se1, Xbuf);
    k_seed <<<dim3(8, NB), 256, 0, stream>>>(Xbuf, ccvP0, combV0);
    for (int t = 0; t < NT; t++) {
        f16* ccvR  = (t & 1) ? ccvP1  : ccvP0;
        f16* ccvW  = (t & 1) ? ccvP0  : ccvP1;
        f16* cvR   = (t & 1) ? combV1 : combV0;
        f16* cvW   = (t & 1) ? combV0 : combV1;
        k_step<<<dim3(8, NB), 256, 0, stream>>>(AcatT, ccvR, cvR, WgF2, bg2, cstT,
                 (t < 23) ? Xbuf + (size_t)(t+1)*sliceH : (const f16*)nullptr,
                 (t == 23) ? hT : (f16*)nullptr, nullptr, nullptr, nullptr, t,
                 ccvW, cvW, t == 0, t < 23);
    }

    // ---- layer 3 (final, fixed input x3 = Wo2.h2_last + bo2) ----
    k_xprojm<<<(NB*512)/128, 256, 0, stream>>>(hT, WoF2, bo2, nullptr, X3);
    k_seed <<<dim3(8, NB), 256, 0, stream>>>(X3, ccvP0, combV0);
    for (int t = 0; t < NT; t++) {
        f16* ccvR  = (t & 1) ? ccvP1  : ccvP0;
        f16* ccvW  = (t & 1) ? ccvP0  : ccvP1;
        f16* cvR   = (t & 1) ? combV1 : combV0;
        f16* cvW   = (t & 1) ? combV0 : combV1;
        k_step<<<dim3(8, NB), 256, 0, stream>>>(AcatT, ccvR, cvR, WgF3, bg3, cstT,
                 X3, nullptr, Wo3, bo3, out, t,
                 ccvW, cvW, t == 0, t < 23);
    }
}

// Round 7
// 5196.448 us; speedup vs baseline: 4.6849x; 1.0168x over previous
//
#include <hip/hip_runtime.h>
#include <math.h>

#define NV 500
#define NB 32
#define NT 24
#define NH 64

typedef _Float16 f16;
typedef _Float16 f16x8 __attribute__((ext_vector_type(8)));
typedef _Float16 f16x4 __attribute__((ext_vector_type(4)));
typedef float    f32x4 __attribute__((ext_vector_type(4)));

__device__ __forceinline__ float sigm(float x){ return 1.f/(1.f+expf(-x)); }

// ======================= prep: A transpose/cast + A^2 via MFMA =======================
// AcatT[j][w][v]: j=2s -> A[s][v][w], j=2s+1 -> A2[s][v][w] (all f16, 512-padded).
// k_prep_a writes the even rows (transpose of A) + A16[s][v][w] (direct cast).
__global__ __launch_bounds__(256)
void k_prep_a(const float* __restrict__ A, f16* __restrict__ AcatT, f16* __restrict__ A16)
{
    __shared__ float t[64][65];
    const int s = blockIdx.z;
    const int v0 = blockIdx.y*64, w0 = blockIdx.x*64;
    const float* As = A + (size_t)s*500*500;
    const int tid = threadIdx.x;
    for (int e = tid; e < 64*64; e += 256) {
        int r = e>>6, c = e&63;
        int v = v0+r, w = w0+c;
        float val = (v < 500 && w < 500) ? As[(size_t)v*500 + w] : 0.f;
        t[r][c] = val;
        A16[((size_t)s*512 + v)*512 + w] = (f16)val;
    }
    __syncthreads();
    for (int e = tid; e < 64*64; e += 256) {
        int wr = e>>6, vc = e&63;
        AcatT[((size_t)(2*s)*512 + w0+wr)*512 + v0+vc] = (f16)t[vc][wr];
    }
}

// D[w][v] = sum_u AT[w][u]*A16[v][u] = A2[v][w]  -> AcatT odd rows. grid (4,4,3).
__global__ __launch_bounds__(256)
void k_a2m(f16* __restrict__ AcatT, const f16* __restrict__ A16)
{
    __shared__ f16 lA[128*32];
    __shared__ f16 lB[128*32];
    const int tid = threadIdx.x;
    const int s = blockIdx.z;
    const int n0 = blockIdx.x*128, m0 = blockIdx.y*128;
    const f16* AT = AcatT + (size_t)(2*s)*512*512;
    const f16* Y  = A16 + (size_t)s*512*512;
    f16* D = AcatT + (size_t)(2*s+1)*512*512;

    const int r0 = tid>>2, c0 = tid&3;
    const int swz0 = r0*32 + ((c0 ^ ((r0>>1)&3))<<3);
    const int swz1 = swz0 + 64*32;
    const f16* gA0 = AT + (size_t)(m0+r0)*512 + c0*8;
    const f16* gA1 = AT + (size_t)(m0+r0+64)*512 + c0*8;
    const f16* gB0 = Y + (size_t)(n0+r0)*512 + c0*8;
    const f16* gB1 = Y + (size_t)(n0+r0+64)*512 + c0*8;

    const int w = tid>>6, lane = tid&63;
    const int wr = (w>>1)<<6, wc = (w&1)<<6;
    const int fm = lane&15, fk = lane>>4;
    const int fch = (fk ^ ((fm>>1)&3))<<3;

    f32x4 acc[4][4];
    #pragma unroll
    for (int i=0;i<4;i++)
        #pragma unroll
        for (int j=0;j<4;j++) acc[i][j] = (f32x4){0.f,0.f,0.f,0.f};

    f32x4 ra0 = *(const f32x4*)gA0, ra1 = *(const f32x4*)gA1;
    f32x4 rb0 = *(const f32x4*)gB0, rb1 = *(const f32x4*)gB1;

    for (int ks = 0; ks < 16; ks++) {
        __syncthreads();
        *(f32x4*)(lA + swz0) = ra0;  *(f32x4*)(lA + swz1) = ra1;
        *(f32x4*)(lB + swz0) = rb0;  *(f32x4*)(lB + swz1) = rb1;
        if (ks < 15) {
            int o = (ks+1)*32;
            ra0 = *(const f32x4*)(gA0 + o); ra1 = *(const f32x4*)(gA1 + o);
            rb0 = *(const f32x4*)(gB0 + o); rb1 = *(const f32x4*)(gB1 + o);
        }
        __syncthreads();
        f16x8 af[4], bf[4];
        #pragma unroll
        for (int i=0;i<4;i++) af[i] = *(const f16x8*)(lA + (wr + i*16 + fm)*32 + fch);
        #pragma unroll
        for (int j=0;j<4;j++) bf[j] = *(const f16x8*)(lB + (wc + j*16 + fm)*32 + fch);
        #pragma unroll
        for (int i=0;i<4;i++)
            #pragma unroll
            for (int j=0;j<4;j++)
                acc[i][j] = __builtin_amdgcn_mfma_f32_16x16x32_f16(af[i], bf[j], acc[i][j], 0, 0, 0);
    }

    #pragma unroll
    for (int j=0;j<4;j++) {
        int col = n0 + wc + j*16 + fm;
        #pragma unroll
        for (int i=0;i<4;i++) {
            int mb = m0 + wr + i*16 + fk*4;
            #pragma unroll
            for (int r=0;r<4;r++)
                D[(size_t)(mb+r)*512 + col] = (f16)acc[i][j][r];
        }
    }
}

__global__ void k_f2h(const float* __restrict__ src, f16* __restrict__ dst, int n)
{
    int idx = blockIdx.x*256 + threadIdx.x;
    if (idx < n) dst[idx] = (f16)src[idx];
}

// ======================= MFMA diffusion GEMM (proven baseline structure) =======================
__global__ __launch_bounds__(256)
void k_diff(const f16* __restrict__ Acv, const f16* __restrict__ Bt,
            f16* __restrict__ fout, int Mtot, int C, int G)
{
    __shared__ f16 lA[128*32];
    __shared__ f16 lB[128*32];
    const int tid = threadIdx.x;
    const int n0 = blockIdx.x*128, m0 = blockIdx.y*128;
    const int r0 = tid>>2, c0 = tid&3;
    const int swz0 = r0*32 + ((c0 ^ ((r0>>1)&3))<<3);
    const int swz1 = swz0 + 64*32;
    int mA0 = m0 + r0;      if (mA0 > Mtot-1) mA0 = Mtot-1;
    int mA1 = m0 + r0 + 64; if (mA1 > Mtot-1) mA1 = Mtot-1;
    const f16* gA0 = Acv + (size_t)mA0*512 + c0*8;
    const f16* gA1 = Acv + (size_t)mA1*512 + c0*8;
    const f16* gB0 = Bt + (size_t)(n0+r0)*512 + c0*8;
    const f16* gB1 = Bt + (size_t)(n0+r0+64)*512 + c0*8;

    const int w = tid>>6, lane = tid&63;
    const int wr = (w>>1)<<6, wc = (w&1)<<6;
    const int fm = lane&15, fk = lane>>4;
    const int fch = (fk ^ ((fm>>1)&3))<<3;

    f32x4 acc[4][4];
    #pragma unroll
    for (int i=0;i<4;i++)
        #pragma unroll
        for (int j=0;j<4;j++) acc[i][j] = (f32x4){0.f,0.f,0.f,0.f};

    f32x4 ra0 = *(const f32x4*)gA0, ra1 = *(const f32x4*)gA1;
    f32x4 rb0 = *(const f32x4*)gB0, rb1 = *(const f32x4*)gB1;

    for (int ks = 0; ks < 16; ks++) {
        __syncthreads();
        *(f32x4*)(lA + swz0) = ra0;  *(f32x4*)(lA + swz1) = ra1;
        *(f32x4*)(lB + swz0) = rb0;  *(f32x4*)(lB + swz1) = rb1;
        if (ks < 15) {
            int o = (ks+1)*32;
            ra0 = *(const f32x4*)(gA0 + o); ra1 = *(const f32x4*)(gA1 + o);
            rb0 = *(const f32x4*)(gB0 + o); rb1 = *(const f32x4*)(gB1 + o);
        }
        __syncthreads();
        f16x8 af[4], bf[4];
        #pragma unroll
        for (int i=0;i<4;i++) af[i] = *(const f16x8*)(lA + (wr + i*16 + fm)*32 + fch);
        #pragma unroll
        for (int j=0;j<4;j++) bf[j] = *(const f16x8*)(lB + (wc + j*16 + fm)*32 + fch);
        #pragma unroll
        for (int i=0;i<4;i++)
            #pragma unroll
            for (int j=0;j<4;j++)
                acc[i][j] = __builtin_amdgcn_mfma_f32_16x16x32_f16(af[i], bf[j], acc[i][j], 0, 0, 0);
    }

    #pragma unroll
    for (int j=0;j<4;j++) {
        int col = n0 + wc + j*16 + fm;
        int jb = col >> 9, wv = col & 511;
        if (wv >= 500) continue;
        #pragma unroll
        for (int i=0;i<4;i++) {
            int mb = m0 + wr + i*16 + fk*4;
            if (C == 64) {
                if (mb >= Mtot) continue;
                int b = mb >> 6, c = mb & 63;
                f16x4 h4;
                h4[0]=(f16)acc[i][j][0]; h4[1]=(f16)acc[i][j][1];
                h4[2]=(f16)acc[i][j][2]; h4[3]=(f16)acc[i][j][3];
                *(f16x4*)(fout + ((size_t)b*512 + wv)*G + C + jb*C + c) = h4;
            } else {
                #pragma unroll
                for (int r=0;r<4;r++) {
                    int m = mb + r;
                    if (m < Mtot) {
                        int b = m / C, c = m - b*C;
                        fout[((size_t)b*512 + wv)*G + C + jb*C + c] = (f16)acc[i][j][r];
                    }
                }
            }
        }
    }
}

// ======================= MFMA gates GEMM (baseline shape; f16 output) =======================
__global__ __launch_bounds__(256)
void k_gates(const f16* __restrict__ fT, const f16* __restrict__ Wg,
             const float* __restrict__ bg, f16* __restrict__ gT)
{
    __shared__ f16 lA[128*32];
    __shared__ f16 lB[128*32];
    const int tid = threadIdx.x;
    const int n0 = blockIdx.x*128, m0 = blockIdx.y*128, b = blockIdx.z;
    const f16* Ab = fT + (size_t)b*512*448;
    const int r0 = tid>>2, c0 = tid&3;
    const int swz0 = r0*32 + ((c0 ^ ((r0>>1)&3))<<3);
    const int swz1 = swz0 + 64*32;
    const f16* gA0 = Ab + (size_t)(m0+r0)*448 + c0*8;
    const f16* gA1 = Ab + (size_t)(m0+r0+64)*448 + c0*8;
    const f16* gB0 = Wg + (size_t)(n0+r0)*448 + c0*8;
    const f16* gB1 = Wg + (size_t)(n0+r0+64)*448 + c0*8;

    const int w = tid>>6, lane = tid&63;
    const int wr = (w>>1)<<6, wc = (w&1)<<6;
    const int fm = lane&15, fk = lane>>4;
    const int fch = (fk ^ ((fm>>1)&3))<<3;

    f32x4 acc[4][4];
    #pragma unroll
    for (int i=0;i<4;i++)
        #pragma unroll
        for (int j=0;j<4;j++) acc[i][j] = (f32x4){0.f,0.f,0.f,0.f};

    f32x4 ra0 = *(const f32x4*)gA0, ra1 = *(const f32x4*)gA1;
    f32x4 rb0 = *(const f32x4*)gB0, rb1 = *(const f32x4*)gB1;

    for (int ks = 0; ks < 14; ks++) {
        __syncthreads();
        *(f32x4*)(lA + swz0) = ra0;  *(f32x4*)(lA + swz1) = ra1;
        *(f32x4*)(lB + swz0) = rb0;  *(f32x4*)(lB + swz1) = rb1;
        if (ks < 13) {
            int o = (ks+1)*32;
            ra0 = *(const f32x4*)(gA0 + o); ra1 = *(const f32x4*)(gA1 + o);
            rb0 = *(const f32x4*)(gB0 + o); rb1 = *(const f32x4*)(gB1 + o);
        }
        __syncthreads();
        f16x8 af[4], bf[4];
        #pragma unroll
        for (int i=0;i<4;i++) af[i] = *(const f16x8*)(lA + (wr + i*16 + fm)*32 + fch);
        #pragma unroll
        for (int j=0;j<4;j++) bf[j] = *(const f16x8*)(lB + (wc + j*16 + fm)*32 + fch);
        #pragma unroll
        for (int i=0;i<4;i++)
            #pragma unroll
            for (int j=0;j<4;j++)
                acc[i][j] = __builtin_amdgcn_mfma_f32_16x16x32_f16(af[i], bf[j], acc[i][j], 0, 0, 0);
    }

    #pragma unroll
    for (int j=0;j<4;j++) {
        int o = n0 + wc + j*16 + fm;
        float bias = bg[o];
        #pragma unroll
        for (int i=0;i<4;i++) {
            int vb = m0 + wr + i*16 + fk*4;
            #pragma unroll
            for (int r=0;r<4;r++) {
                int v = vb + r;
                if (v < 500)
                    gT[((size_t)b*512 + v)*256 + o] = (f16)(acc[i][j][r] + bias);
            }
        }
    }
}

// ======================= fused LSTM + next-step comb (layers 1-3) =======================
__global__ __launch_bounds__(256)
void k_lstmcomb(const f16* __restrict__ gT, float* __restrict__ cst,
                const f16* __restrict__ Xn, f16* __restrict__ hsave,
                const float* __restrict__ Wo3, const float* __restrict__ bo3,
                float* __restrict__ out, int t,
                f16* __restrict__ fT, f16* __restrict__ ccv,
                int first, int writecomb)
{
    __shared__ f16 combS[64*68];
    const int b = blockIdx.y, v0 = blockIdx.x*64;
    const int tid = threadIdx.x, vl = tid>>2, p = tid&3;
    const int v = v0 + vl;
    const size_t row = (size_t)b*512 + v;
    const f16* g = gT + row*256 + (p<<4);
    alignas(16) f16 gq[4][16];
    #pragma unroll
    for (int q = 0; q < 4; q++) {
        *(f32x4*)&gq[q][0] = *(const f32x4*)(g + q*64);
        *(f32x4*)&gq[q][8] = *(const f32x4*)(g + q*64 + 8);
    }

    float* cp = cst + row*64 + (p<<4);
    float hy[16];
    #pragma unroll
    for (int k4 = 0; k4 < 4; k4++) {
        f32x4 cx4 = first ? (f32x4){0.f,0.f,0.f,0.f} : *(const f32x4*)(cp + k4*4);
        f32x4 cy4;
        #pragma unroll
        for (int e = 0; e < 4; e++) {
            int kk = k4*4+e;
            float gi = (float)gq[0][kk], gf = (float)gq[1][kk];
            float gc = (float)gq[2][kk], go = (float)gq[3][kk];
            float cy = sigm(gf)*cx4[e] + sigm(gi)*gc;
            cy4[e] = cy;
            hy[kk] = sigm(go)*tanhf(cy);
        }
        *(f32x4*)(cp + k4*4) = cy4;
    }

    if (hsave) {
        alignas(16) f16 tmp[16];
        #pragma unroll
        for (int k=0;k<16;k++) tmp[k] = (f16)hy[k];
        f16* hp = hsave + row*64 + (p<<4);
        *(f32x4*)hp = *(f32x4*)tmp;
        *(f32x4*)(hp+8) = *(f32x4*)(tmp+8);
    }

    if (out) {
        float r0 = 0.f, r1 = 0.f;
        #pragma unroll
        for (int k=0;k<16;k++){ r0 += Wo3[(p<<4)+k]*hy[k]; r1 += Wo3[64+(p<<4)+k]*hy[k]; }
        r0 += __shfl_xor(r0, 1, 64); r0 += __shfl_xor(r0, 2, 64);
        r1 += __shfl_xor(r1, 1, 64); r1 += __shfl_xor(r1, 2, 64);
        if (p == 0 && v < 500) {
            out[((size_t)(b*2+0)*500 + v)*24 + t] = r0 + bo3[0];
            out[((size_t)(b*2+1)*500 + v)*24 + t] = r1 + bo3[1];
        }
    }

    if (writecomb) {
        alignas(16) f16 c16[16];
        if (v < 500) {
            const f16* xp = Xn + row*64 + (p<<4);
            alignas(16) f16 xv[16];
            *(f32x4*)xv = *(const f32x4*)xp;
            *(f32x4*)(xv+8) = *(const f32x4*)(xp+8);
            #pragma unroll
            for (int k=0;k<16;k++) c16[k] = (f16)((float)xv[k] + hy[k]);
        } else {
            #pragma unroll
            for (int k=0;k<16;k++) c16[k] = (f16)0.f;
        }
        f16* fp = fT + row*448 + (p<<4);
        *(f32x4*)fp = *(f32x4*)c16;
        *(f32x4*)(fp+8) = *(f32x4*)(c16+8);
        #pragma unroll
        for (int k=0;k<16;k++) combS[vl*68 + (p<<4) + k] = c16[k];
        __syncthreads();
        const int c = tid>>2, jj = tid&3;
        alignas(16) f16 tmp[16];
        #pragma unroll
        for (int k=0;k<16;k++) tmp[k] = combS[(jj*16+k)*68 + c];
        f16* dst = ccv + ((size_t)b*64 + c)*512 + v0 + jj*16;
        *(f32x4*)dst = *(f32x4*)tmp;
        *(f32x4*)(dst+8) = *(f32x4*)(tmp+8);
    }
}

// ======================= seed comb for t=0 (big layers) =======================
__global__ __launch_bounds__(256)
void k_seed(const f16* __restrict__ X0, f16* __restrict__ fT, f16* __restrict__ ccv)
{
    __shared__ f16 combS[64*68];
    const int b = blockIdx.y, v0 = blockIdx.x*64;
    const int tid = threadIdx.x, vl = tid>>2, p = tid&3;
    const int v = v0 + vl;
    const size_t row = (size_t)b*512 + v;
    alignas(16) f16 c16[16];
    if (v < 500) {
        const f16* xp = X0 + row*64 + p*16;
        *(f32x4*)c16 = *(const f32x4*)xp;
        *(f32x4*)(c16+8) = *(const f32x4*)(xp+8);
    } else {
        #pragma unroll
        for (int k=0;k<16;k++) c16[k] = (f16)0.f;
    }
    f16* fp = fT + row*448 + p*16;
    *(f32x4*)fp = *(f32x4*)c16;
    *(f32x4*)(fp+8) = *(f32x4*)(c16+8);
    #pragma unroll
    for (int k=0;k<16;k++) combS[vl*68 + p*16 + k] = c16[k];
    __syncthreads();
    const int c = tid>>2, j = tid&3;
    alignas(16) f16 tmp[16];
    #pragma unroll
    for (int k=0;k<16;k++) tmp[k] = combS[(j*16+k)*68 + c];
    f16* dst = ccv + ((size_t)b*64 + c)*512 + v0 + j*16;
    *(f32x4*)dst = *(f32x4*)tmp;
    *(f32x4*)(dst+8) = *(f32x4*)(tmp+8);
}

// ======================= MFMA input projection (Cin=64, f16 src) =======================
__global__ __launch_bounds__(256)
void k_xprojm(const f16* __restrict__ src, const f16* __restrict__ WoF,
              const float* __restrict__ bo, const float* __restrict__ se,
              f16* __restrict__ X)
{
    __shared__ f16 lA[128*64];
    __shared__ f16 lB[64*64];
    const int tid = threadIdx.x;
    const size_t m0 = (size_t)blockIdx.x*128;
    const int r0 = tid>>2, c0 = tid&3;
    const int swz = r0*32 + ((c0 ^ ((r0>>1)&3))<<3);
    const f16* gA0 = src + (m0 + r0)*64 + c0*8;
    const f16* gA1 = gA0 + 64*64;
    const f16* gB  = WoF + r0*64 + c0*8;

    *(f32x4*)(lA + swz)               = *(const f32x4*)gA0;
    *(f32x4*)(lA + 2048 + swz)        = *(const f32x4*)gA1;
    *(f32x4*)(lA + 4096 + swz)        = *(const f32x4*)(gA0 + 32);
    *(f32x4*)(lA + 6144 + swz)        = *(const f32x4*)(gA1 + 32);
    *(f32x4*)(lB + swz)               = *(const f32x4*)gB;
    *(f32x4*)(lB + 2048 + swz)        = *(const f32x4*)(gB + 32);
    __syncthreads();

    const int w = tid>>6, lane = tid&63;
    const int wr = w<<5;
    const int fm = lane&15, fk = lane>>4;
    const int fch = (fk ^ ((fm>>1)&3))<<3;

    f32x4 acc[2][4];
    #pragma unroll
    for (int i=0;i<2;i++)
        #pragma unroll
        for (int j=0;j<4;j++) acc[i][j] = (f32x4){0.f,0.f,0.f,0.f};

    #pragma unroll
    for (int ks=0; ks<2; ks++) {
        f16x8 af[2], bf[4];
        #pragma unroll
        for (int i=0;i<2;i++) af[i] = *(const f16x8*)(lA + ks*4096 + (wr + i*16 + fm)*32 + fch);
        #pragma unroll
        for (int j=0;j<4;j++) bf[j] = *(const f16x8*)(lB + ks*2048 + (j*16 + fm)*32 + fch);
        #pragma unroll
        for (int i=0;i<2;i++)
            #pragma unroll
            for (int j=0;j<4;j++)
                acc[i][j] = __builtin_amdgcn_mfma_f32_16x16x32_f16(af[i], bf[j], acc[i][j], 0, 0, 0);
    }
    __syncthreads();

    const int bb = (int)((m0 >> 9) & 31);
    #pragma unroll
    for (int j=0;j<4;j++) {
        const int c = (j<<4) + fm;
        const float bias = bo[c];
        const float sf = se ? se[bb*64 + c] : 1.f;
        #pragma unroll
        for (int i=0;i<2;i++) {
            const int rbase = wr + i*16 + (fk<<2);
            #pragma unroll
            for (int r=0;r<4;r++)
                lA[(rbase + r)*64 + c] = (f16)(sf*(acc[i][j][r] + bias));
        }
    }
    __syncthreads();
    #pragma unroll
    for (int pass=0; pass<4; pass++) {
        int chunk = pass*256 + tid;
        int row = chunk>>3, off = (chunk&7)<<3;
        *(f32x4*)(X + (m0 + row)*64 + off) = *(const f32x4*)(lA + row*64 + off);
    }
}

// ======================= scalar input projection (Cin=6, f32 src, layer 1) =======================
__global__ void k_xproj1(const float* __restrict__ src, const float* __restrict__ Wo,
                         const float* __restrict__ bo, const float* __restrict__ se,
                         f16* __restrict__ X, int total)
{
    int id = blockIdx.x*256 + threadIdx.x;
    if (id >= total) return;
    int c = id & 63;
    size_t row = (size_t)(id >> 6);
    int b = (int)((row >> 9) & 31);
    const float* sp = src + row*6;
    float a = bo[c];
    #pragma unroll
    for (int j=0;j<6;j++) a += Wo[c*6+j]*sp[j];
    X[id] = (f16)(se[b*64+c]*a);
}

// ======================= layer 0 =======================
__global__ void k_xe(const float* __restrict__ x, const int* __restrict__ wt,
                     const float* __restrict__ Wemb, float* __restrict__ XE)
{
    int id = blockIdx.x*256 + threadIdx.x;
    if (id >= NT*NB*512) return;
    int v = id & 511; int r = id >> 9; int b = r & 31; int t = r >> 5;
    float vals[6] = {0.f,0.f,0.f,0.f,0.f,0.f};
    if (v < 500) {
        vals[0] = x[((size_t)(b*2+0)*500 + v)*24 + t];
        vals[1] = x[((size_t)(b*2+1)*500 + v)*24 + t];
        int wty = wt[((size_t)b*500 + v)*24 + t];
        vals[2] = Wemb[wty*4+0]; vals[3] = Wemb[wty*4+1];
        vals[4] = Wemb[wty*4+2]; vals[5] = Wemb[wty*4+3];
    }
    float* xe = XE + (size_t)id*6;
    #pragma unroll
    for (int c = 0; c < 6; c++) xe[c] = vals[c];
}

__global__ void k_seed0(const float* __restrict__ XE, f16* __restrict__ f0T,
                        f16* __restrict__ ccv0)
{
    int id = blockIdx.x*256 + threadIdx.x;
    if (id >= NB*512) return;
    int v = id & 511, b = id >> 9;
    const float* xe = XE + (size_t)id*6;
    #pragma unroll
    for (int c = 0; c < 6; c++) {
        f16 h = (v < 500) ? (f16)xe[c] : (f16)0.f;
        f0T[(size_t)id*42 + c] = h;
        ccv0[((size_t)b*6 + c)*512 + v] = h;
    }
}

__global__ __launch_bounds__(256)
void k_glstm0(f16* f0T, const float* __restrict__ Wg0,
              const float* __restrict__ bg0, float* __restrict__ cst0,
              float* __restrict__ hs0T, const float* __restrict__ XE,
              f16* __restrict__ ccv0, int t)
{
    __shared__ float WgS[24*42];
    __shared__ float bgS[24];
    int tid = threadIdx.x;
    for (int i = tid; i < 24*42; i += 256) WgS[i] = Wg0[i];
    if (tid < 24) bgS[tid] = bg0[tid];
    __syncthreads();
    int id = blockIdx.x*256 + tid;
    if (id >= NB*500) return;
    int b = id / 500, v = id - b*500;
    const f16* fp = f0T + ((size_t)b*512 + v)*42;
    float fv[42];
    #pragma unroll
    for (int g = 0; g < 42; g++) fv[g] = (float)fp[g];
    float gates[24];
    #pragma unroll
    for (int o = 0; o < 24; o++) {
        float a = bgS[o];
        #pragma unroll
        for (int g = 0; g < 42; g++) a += WgS[o*42+g]*fv[g];
        gates[o] = a;
    }
    size_t hrow = (((size_t)t*NB + b)*512 + v)*6;
    const float* xe = XE + (((size_t)(t+1)*NB + b)*512 + v)*6;   // only read if t<23
    #pragma unroll
    for (int c = 0; c < 6; c++) {
        size_t ci = ((size_t)b*500 + v)*6 + c;
        float cx = t ? cst0[ci] : 0.f;
        float cy = sigm(gates[6+c])*cx + sigm(gates[c])*gates[12+c];
        cst0[ci] = cy;
        float h = sigm(gates[18+c])*tanhf(cy);
        hs0T[hrow + c] = h;
        if (t < 23) {
            float cmb = xe[c] + h;
            f0T[((size_t)b*512 + v)*42 + c] = (f16)cmb;
            ccv0[((size_t)b*6 + c)*512 + v] = (f16)cmb;
        }
    }
}

// ======================= SE path =======================
__global__ void k_mean0(const float* __restrict__ hs0T, float* __restrict__ mean0)
{
    int b = blockIdx.x;
    float acc[6] = {0,0,0,0,0,0};
    for (int i = threadIdx.x; i < 24*500; i += 256) {
        int tt = i/500, v = i - tt*500;
        const float* p = hs0T + (((size_t)tt*NB + b)*512 + v)*6;
        #pragma unroll
        for (int c=0;c<6;c++) acc[c] += p[c];
    }
    __shared__ float red[256];
    for (int c=0;c<6;c++) {
        red[threadIdx.x] = acc[c]; __syncthreads();
        for (int s=128;s>0;s>>=1) { if (threadIdx.x<s) red[threadIdx.x]+=red[threadIdx.x+s]; __syncthreads(); }
        if (threadIdx.x==0) mean0[b*6+c] = red[0]/12000.f;
        __syncthreads();
    }
}

__global__ void k_mean1(const f16* __restrict__ hs1T, float* __restrict__ mean1)
{
    int cg = blockIdx.x, b = blockIdx.y;
    float acc[8] = {0,0,0,0,0,0,0,0};
    for (int i = threadIdx.x; i < 24*500; i += 256) {
        int tt = i/500, v = i - tt*500;
        const f16* p = hs1T + (((size_t)tt*NB + b)*512 + v)*64 + cg*8;
        #pragma unroll
        for (int c=0;c<8;c++) acc[c] += (float)p[c];
    }
    __shared__ float red[256];
    for (int c=0;c<8;c++) {
        red[threadIdx.x] = acc[c]; __syncthreads();
        for (int s=128;s>0;s>>=1) { if (threadIdx.x<s) red[threadIdx.x]+=red[threadIdx.x+s]; __syncthreads(); }
        if (threadIdx.x==0) mean1[b*64 + cg*8 + c] = red[0]/12000.f;
        __syncthreads();
    }
}

__global__ void k_se(const float* __restrict__ meanhs, const float* __restrict__ Wo,
                     const float* __restrict__ bo, int Cin,
                     const float* __restrict__ Wa, const float* __restrict__ Wb,
                     float* __restrict__ se)
{
    int b = blockIdx.x; int c = threadIdx.x;
    __shared__ float y[64]; __shared__ float a[4];
    float acc = bo[c];
    for (int j = 0; j < Cin; j++) acc += Wo[(size_t)c*Cin + j] * meanhs[b*Cin + j];
    y[c] = acc;
    __syncthreads();
    if (c < 4) {
        float s = 0.f;
        for (int j = 0; j < 64; j++) s += Wa[c*64 + j] * y[j];
        a[c] = fmaxf(s, 0.f);
    }
    __syncthreads();
    float s = 0.f;
    #pragma unroll
    for (int j = 0; j < 4; j++) s += Wb[c*4 + j] * a[j];
    se[b*64 + c] = 1.f/(1.f + expf(-s));
}

// ======================= host launch =======================
extern "C" void kernel_launch(void* const* d_in, const int* in_sizes, int n_in,
                              void* d_out, int out_size, void* d_ws, size_t ws_size,
                              hipStream_t stream)
{
    const float* x    = (const float*)d_in[0];
    const float* sup  = (const float*)d_in[1];
    const int*   wt   = (const int*)  d_in[2];
    const float* Wemb = (const float*)d_in[3];
    const float* Wg0  = (const float*)d_in[4];
    const float* bg0  = (const float*)d_in[5];
    const float* Wo0  = (const float*)d_in[6];
    const float* bo0  = (const float*)d_in[7];
    const float* Wa0  = (const float*)d_in[8];
    const float* Wb0  = (const float*)d_in[9];
    const float* Wg1  = (const float*)d_in[10];
    const float* bg1  = (const float*)d_in[11];
    const float* Wo1  = (const float*)d_in[12];
    const float* bo1  = (const float*)d_in[13];
    const float* Wa1  = (const float*)d_in[14];
    const float* Wb1  = (const float*)d_in[15];
    const float* Wg2  = (const float*)d_in[16];
    const float* bg2  = (const float*)d_in[17];
    const float* Wo2  = (const float*)d_in[18];
    const float* bo2  = (const float*)d_in[19];
    const float* Wg3  = (const float*)d_in[20];
    const float* bg3  = (const float*)d_in[21];
    const float* Wo3  = (const float*)d_in[22];
    const float* bo3  = (const float*)d_in[23];
    float* out = (float*)d_out;
    (void)in_sizes; (void)n_in; (void)out_size; (void)ws_size;

    char* ws = (char*)d_ws;
    size_t off = 0;
    f16*   AcatT  = (f16*)(ws + off);   off += (size_t)3072*512*2;
    f16*   A16    = (f16*)(ws + off);   off += (size_t)3*512*512*2;
    f16*   WgF1   = (f16*)(ws + off);   off += (size_t)256*448*2;
    f16*   WgF2   = (f16*)(ws + off);   off += (size_t)256*448*2;
    f16*   WgF3   = (f16*)(ws + off);   off += (size_t)256*448*2;
    f16*   WoF1   = (f16*)(ws + off);   off += (size_t)64*64*2;
    f16*   WoF2   = (f16*)(ws + off);   off += (size_t)64*64*2;
    f16*   comb_cv= (f16*)(ws + off);   off += (size_t)2048*512*2;
    f16*   ccv0   = (f16*)(ws + off);   off += (size_t)192*512*2;
    f16*   featsT = (f16*)(ws + off);   off += (size_t)NB*512*448*2;
    f16*   f0T    = (f16*)(ws + off);   off += (size_t)NB*512*42*2;
    f16*   gatesT = (f16*)(ws + off);   off += (size_t)NB*512*256*2;
    float* XE     = (float*)(ws + off); off += (size_t)NT*NB*512*6*4;
    float* hs0T   = (float*)(ws + off); off += (size_t)NT*NB*512*6*4;
    f16*   hs1T   = (f16*)(ws + off);   off += (size_t)NT*NB*512*64*2;
    f16*   hT     = (f16*)(ws + off);   off += (size_t)NB*512*64*2;
    float* cstT   = (float*)(ws + off); off += (size_t)NB*512*64*4;
    float* cst0   = (float*)(ws + off); off += (size_t)NB*500*6*4;
    f16*   Xbuf   = (f16*)(ws + off);   off += (size_t)NT*NB*512*64*2;
    f16*   X3     = (f16*)(ws + off);   off += (size_t)NB*512*64*2;
    float* mean0  = (float*)(ws + off); off += 8192;
    float* se0    = (float*)(ws + off); off += 8192;
    float* mean1  = (float*)(ws + off); off += 8192;
    float* se1    = (float*)(ws + off); off += 8192;

    const size_t sliceH = (size_t)NB*512*64;
    const size_t slice0 = 0;
    (void)slice0;

    // ---- prep ----
    k_prep_a<<<dim3(8, 8, 3), 256, 0, stream>>>(sup, AcatT, A16);
    k_a2m   <<<dim3(4, 4, 3), 256, 0, stream>>>(AcatT, A16);
    k_f2h <<<(256*448 + 255)/256, 256, 0, stream>>>(Wg1, WgF1, 256*448);
    k_f2h <<<(256*448 + 255)/256, 256, 0, stream>>>(Wg2, WgF2, 256*448);
    k_f2h <<<(256*448 + 255)/256, 256, 0, stream>>>(Wg3, WgF3, 256*448);
    k_f2h <<<16, 256, 0, stream>>>(Wo1, WoF1, 64*64);
    k_f2h <<<16, 256, 0, stream>>>(Wo2, WoF2, 64*64);
    k_xe  <<<(NT*NB*512)/256, 256, 0, stream>>>(x, wt, Wemb, XE);

    // ---- layer 0 ----
    k_seed0<<<(NB*512)/256, 256, 0, stream>>>(XE, f0T, ccv0);
    for (int t = 0; t < NT; t++) {
        k_diff  <<<dim3(24, 2), 256, 0, stream>>>(ccv0, AcatT, f0T, 192, 6, 42);
        k_glstm0<<<(NB*500 + 255)/256, 256, 0, stream>>>(f0T, Wg0, bg0, cst0, hs0T, XE, ccv0, t);
    }
    k_mean0<<<NB, 256, 0, stream>>>(hs0T, mean0);
    k_se   <<<NB, 64, 0, stream>>>(mean0, Wo0, bo0, 6, Wa0, Wb0, se0);

    // ---- layer 1 ----
    k_xproj1<<<(NT*NB*512*64)/256, 256, 0, stream>>>(hs0T, Wo0, bo0, se0, Xbuf, NT*NB*512*64);
    k_seed <<<dim3(8, NB), 256, 0, stream>>>(Xbuf, featsT, comb_cv);
    for (int t = 0; t < NT; t++) {
        k_diff <<<dim3(24, 16), 256, 0, stream>>>(comb_cv, AcatT, featsT, 2048, 64, 448);
        k_gates<<<dim3(2, 4, NB), 256, 0, stream>>>(featsT, WgF1, bg1, gatesT);
        k_lstmcomb<<<dim3(8, NB), 256, 0, stream>>>(gatesT, cstT,
                 (t < 23) ? Xbuf + (size_t)(t+1)*sliceH : (const f16*)nullptr,
                 hs1T + (size_t)t*sliceH, nullptr, nullptr, nullptr, t,
                 featsT, comb_cv, t == 0, t < 23);
    }
    k_mean1<<<dim3(8, NB), 256, 0, stream>>>(hs1T, mean1);
    k_se   <<<NB, 64, 0, stream>>>(mean1, Wo1, bo1, 64, Wa1, Wb1, se1);

    // ---- layer 2 ----
    k_xprojm<<<(NT*NB*512)/128, 256, 0, stream>>>(hs1T, WoF1, bo1, se1, Xbuf);
    k_seed <<<dim3(8, NB), 256, 0, stream>>>(Xbuf, featsT, comb_cv);
    for (int t = 0; t < NT; t++) {
        k_diff <<<dim3(24, 16), 256, 0, stream>>>(comb_cv, AcatT, featsT, 2048, 64, 448);
        k_gates<<<dim3(2, 4, NB), 256, 0, stream>>>(featsT, WgF2, bg2, gatesT);
        k_lstmcomb<<<dim3(8, NB), 256, 0, stream>>>(gatesT, cstT,
                 (t < 23) ? Xbuf + (size_t)(t+1)*sliceH : (const f16*)nullptr,
                 (t == 23) ? hT : (f16*)nullptr, nullptr, nullptr, nullptr, t,
                 featsT, comb_cv, t == 0, t < 23);
    }

    // ---- layer 3 (final, fixed input x3 = Wo2.h2_last + bo2) ----
    k_xprojm<<<(NB*512)/128, 256, 0, stream>>>(hT, WoF2, bo2, nullptr, X3);
    k_seed <<<dim3(8, NB), 256, 0, stream>>>(X3, featsT, comb_cv);
    for (int t = 0; t < NT; t++) {
        k_diff <<<dim3(24, 16), 256, 0, stream>>>(comb_cv, AcatT, featsT, 2048, 64, 448);
        k_gates<<<dim3(2, 4, NB), 256, 0, stream>>>(featsT, WgF3, bg3, gatesT);
        k_lstmcomb<<<dim3(8, NB), 256, 0, stream>>>(gatesT, cstT, X3,
                 nullptr, Wo3, bo3, out, t,
                 featsT, comb_cv, t == 0, t < 23);
    }
}